// Round 1
// baseline (2660.794 us; speedup 1.0000x reference)
//
#include <hip/hip_runtime.h>
#include <hip/hip_bf16.h>
#include <math.h>

#define S_LEN 2048
#define DMODEL 1024
#define NH 16
#define HD 64
#define MLPD 4096
#define BSZ 2
#define NROWS (BSZ * S_LEN) /* 4096 */
#define LOGMAX 4.60517018598809f /* log(1/0.01) */

// ---------------------------------------------------------------- LayerNorm
__global__ __launch_bounds__(256) void ln_f32(const float* __restrict__ x,
                                              const float* __restrict__ g,
                                              const float* __restrict__ b,
                                              float* __restrict__ out) {
  const int row = blockIdx.x;
  const int t = threadIdx.x;
  const float* xr = x + (size_t)row * DMODEL;
  float4 v = *reinterpret_cast<const float4*>(xr + t * 4);
  float s = v.x + v.y + v.z + v.w;
  float s2 = v.x * v.x + v.y * v.y + v.z * v.z + v.w * v.w;
#pragma unroll
  for (int off = 32; off > 0; off >>= 1) {
    s += __shfl_down(s, off);
    s2 += __shfl_down(s2, off);
  }
  __shared__ float red[8];
  __shared__ float mv[2];
  const int wid = t >> 6, lane = t & 63;
  if (lane == 0) { red[wid] = s; red[wid + 4] = s2; }
  __syncthreads();
  if (t == 0) {
    float ts = red[0] + red[1] + red[2] + red[3];
    float ts2 = red[4] + red[5] + red[6] + red[7];
    float mu = ts * (1.0f / DMODEL);
    float var = ts2 * (1.0f / DMODEL) - mu * mu;
    mv[0] = mu;
    mv[1] = rsqrtf(var + 1e-6f);
  }
  __syncthreads();
  const float mu = mv[0], rs = mv[1];
  float4 gv = *reinterpret_cast<const float4*>(g + t * 4);
  float4 bv = *reinterpret_cast<const float4*>(b + t * 4);
  float4 o;
  o.x = (v.x - mu) * rs * gv.x + bv.x;
  o.y = (v.y - mu) * rs * gv.y + bv.y;
  o.z = (v.z - mu) * rs * gv.z + bv.z;
  o.w = (v.w - mu) * rs * gv.w + bv.w;
  *reinterpret_cast<float4*>(out + (size_t)row * DMODEL + t * 4) = o;
}

// ------------------------------------------------------- weight/bias concat
__global__ void concat_w(const float* __restrict__ wq, const float* __restrict__ wk,
                         const float* __restrict__ wv, const float* __restrict__ bq,
                         const float* __restrict__ bk, const float* __restrict__ bv,
                         float* __restrict__ wqkv, float* __restrict__ bqkv) {
  int t = blockIdx.x * blockDim.x + threadIdx.x;
  if (t < 3 * DMODEL) {
    bqkv[t] = t < DMODEL ? bq[t] : (t < 2 * DMODEL ? bk[t - DMODEL] : bv[t - 2 * DMODEL]);
  }
  const int total = DMODEL * 3 * DMODEL;
  for (int idx = t; idx < total; idx += gridDim.x * blockDim.x) {
    int r = idx / (3 * DMODEL);
    int c = idx - r * (3 * DMODEL);
    float val;
    if (c < DMODEL) val = wq[r * DMODEL + c];
    else if (c < 2 * DMODEL) val = wk[r * DMODEL + c - DMODEL];
    else val = wv[r * DMODEL + c - 2 * DMODEL];
    wqkv[idx] = val;
  }
}

// ----------------------------------------------------------------- fp32 GEMM
// C[M,N] = A[M,K] @ B[K,N] + bias (+gelu | +residual)
// 128x128 tile, BK=16, 256 threads, 8x8 per-thread micro-tile.
#define EPI_BIAS 0
#define EPI_GELU 1
#define EPI_RES 2

template <int EPI>
__global__ __launch_bounds__(256) void gemm_f32(const float* __restrict__ A,
                                                const float* __restrict__ B,
                                                const float* __restrict__ bias,
                                                const float* __restrict__ res,
                                                float* __restrict__ C,
                                                int M, int N, int K) {
  __shared__ float As[16][132]; // [k][m], padded
  __shared__ float Bs[16][128]; // [k][n]
  const int tid = threadIdx.x;
  const int tx = tid & 15, ty = tid >> 4;
  const int n0 = blockIdx.x * 128, m0 = blockIdx.y * 128;

  float acc[8][8];
#pragma unroll
  for (int i = 0; i < 8; ++i)
#pragma unroll
    for (int j = 0; j < 8; ++j) acc[i][j] = 0.0f;

  for (int k0 = 0; k0 < K; k0 += 16) {
#pragma unroll
    for (int i = 0; i < 2; ++i) {
      int f = tid + i * 256;
      // A tile: 128 rows x 16 cols = 512 float4 (4 per row)
      int row = f >> 2, c4 = (f & 3) << 2;
      float4 av = *reinterpret_cast<const float4*>(A + (size_t)(m0 + row) * K + k0 + c4);
      As[c4 + 0][row] = av.x;
      As[c4 + 1][row] = av.y;
      As[c4 + 2][row] = av.z;
      As[c4 + 3][row] = av.w;
      // B tile: 16 rows x 128 cols = 512 float4 (32 per row)
      int rowb = f >> 5, cb = (f & 31) << 2;
      *reinterpret_cast<float4*>(&Bs[rowb][cb]) =
          *reinterpret_cast<const float4*>(B + (size_t)(k0 + rowb) * N + n0 + cb);
    }
    __syncthreads();
#pragma unroll
    for (int kk = 0; kk < 16; ++kk) {
      float4 a0 = *reinterpret_cast<const float4*>(&As[kk][ty * 8]);
      float4 a1 = *reinterpret_cast<const float4*>(&As[kk][ty * 8 + 4]);
      float4 b0 = *reinterpret_cast<const float4*>(&Bs[kk][tx * 8]);
      float4 b1 = *reinterpret_cast<const float4*>(&Bs[kk][tx * 8 + 4]);
      float ar[8] = {a0.x, a0.y, a0.z, a0.w, a1.x, a1.y, a1.z, a1.w};
      float br[8] = {b0.x, b0.y, b0.z, b0.w, b1.x, b1.y, b1.z, b1.w};
#pragma unroll
      for (int i = 0; i < 8; ++i)
#pragma unroll
        for (int j = 0; j < 8; ++j) acc[i][j] += ar[i] * br[j];
    }
    __syncthreads();
  }

  // epilogue
  float bias8[8];
  {
    float4 c0 = *reinterpret_cast<const float4*>(bias + n0 + tx * 8);
    float4 c1 = *reinterpret_cast<const float4*>(bias + n0 + tx * 8 + 4);
    bias8[0] = c0.x; bias8[1] = c0.y; bias8[2] = c0.z; bias8[3] = c0.w;
    bias8[4] = c1.x; bias8[5] = c1.y; bias8[6] = c1.z; bias8[7] = c1.w;
  }
#pragma unroll
  for (int i = 0; i < 8; ++i) {
    size_t row = (size_t)(m0 + ty * 8 + i);
    size_t base = row * N + n0 + tx * 8;
    float v[8];
#pragma unroll
    for (int j = 0; j < 8; ++j) {
      float t = acc[i][j] + bias8[j];
      if (EPI == EPI_GELU) t = 0.5f * t * (1.0f + erff(t * 0.70710678118654752f));
      v[j] = t;
    }
    if (EPI == EPI_RES) {
      float4 r0 = *reinterpret_cast<const float4*>(res + base);
      float4 r1 = *reinterpret_cast<const float4*>(res + base + 4);
      v[0] += r0.x; v[1] += r0.y; v[2] += r0.z; v[3] += r0.w;
      v[4] += r1.x; v[5] += r1.y; v[6] += r1.z; v[7] += r1.w;
    }
    float4 o0 = {v[0], v[1], v[2], v[3]};
    float4 o1 = {v[4], v[5], v[6], v[7]};
    *reinterpret_cast<float4*>(C + base) = o0;
    *reinterpret_cast<float4*>(C + base + 4) = o1;
  }
}

// ----------------------------------------------------------- flash attention
// cosine attention: p = exp(scale*(qn.kn - 1)); fixed shift (scores <= scale),
// so no online max is needed. Q-tile 64 rows per block, iterate K/V tiles.
__global__ __launch_bounds__(256) void flash_attn(const float* __restrict__ qkv,
                                                  const float* __restrict__ logit_scale,
                                                  float* __restrict__ ctx) {
  const int qt = blockIdx.x;       // S/64 q tiles
  const int bh = blockIdx.y;       // B*H
  const int b = bh >> 4, h = bh & 15;
  const int tid = threadIdx.x;
  const int tx = tid & 15, ty = tid >> 4;

  __shared__ float Qs[64][68];
  __shared__ float Ks[64][68];
  __shared__ float Vs[64][68];
  __shared__ float Ps[64][68];
  __shared__ float den[64];

  const float scale = __expf(fminf(logit_scale[h], LOGMAX));
  const int r = tid >> 2, c0 = (tid & 3) << 4;

  // load Q tile + l2norm (HD=64 fits the tile, so each row's norm is local)
  {
    const float* src = qkv + ((size_t)(b * S_LEN + qt * 64 + r)) * (3 * DMODEL) + h * HD + c0;
    float4 v0 = *reinterpret_cast<const float4*>(src);
    float4 v1 = *reinterpret_cast<const float4*>(src + 4);
    float4 v2 = *reinterpret_cast<const float4*>(src + 8);
    float4 v3 = *reinterpret_cast<const float4*>(src + 12);
    float ss = v0.x * v0.x + v0.y * v0.y + v0.z * v0.z + v0.w * v0.w +
               v1.x * v1.x + v1.y * v1.y + v1.z * v1.z + v1.w * v1.w +
               v2.x * v2.x + v2.y * v2.y + v2.z * v2.z + v2.w * v2.w +
               v3.x * v3.x + v3.y * v3.y + v3.z * v3.z + v3.w * v3.w;
    ss += __shfl_xor(ss, 1);
    ss += __shfl_xor(ss, 2);
    float inv = 1.0f / fmaxf(sqrtf(ss), 1e-12f);
    float4 o;
    o.x = v0.x * inv; o.y = v0.y * inv; o.z = v0.z * inv; o.w = v0.w * inv;
    *reinterpret_cast<float4*>(&Qs[r][c0]) = o;
    o.x = v1.x * inv; o.y = v1.y * inv; o.z = v1.z * inv; o.w = v1.w * inv;
    *reinterpret_cast<float4*>(&Qs[r][c0 + 4]) = o;
    o.x = v2.x * inv; o.y = v2.y * inv; o.z = v2.z * inv; o.w = v2.w * inv;
    *reinterpret_cast<float4*>(&Qs[r][c0 + 8]) = o;
    o.x = v3.x * inv; o.y = v3.y * inv; o.z = v3.z * inv; o.w = v3.w * inv;
    *reinterpret_cast<float4*>(&Qs[r][c0 + 12]) = o;
  }
  if (tid < 64) den[tid] = 0.0f;
  float acc[4][4];
#pragma unroll
  for (int i = 0; i < 4; ++i)
#pragma unroll
    for (int j = 0; j < 4; ++j) acc[i][j] = 0.0f;
  __syncthreads();

  for (int kt = 0; kt < S_LEN / 64; ++kt) {
    // load K (normalized) and V (raw)
    {
      const float* ksrc = qkv + ((size_t)(b * S_LEN + kt * 64 + r)) * (3 * DMODEL) + DMODEL + h * HD + c0;
      float4 v0 = *reinterpret_cast<const float4*>(ksrc);
      float4 v1 = *reinterpret_cast<const float4*>(ksrc + 4);
      float4 v2 = *reinterpret_cast<const float4*>(ksrc + 8);
      float4 v3 = *reinterpret_cast<const float4*>(ksrc + 12);
      float ss = v0.x * v0.x + v0.y * v0.y + v0.z * v0.z + v0.w * v0.w +
                 v1.x * v1.x + v1.y * v1.y + v1.z * v1.z + v1.w * v1.w +
                 v2.x * v2.x + v2.y * v2.y + v2.z * v2.z + v2.w * v2.w +
                 v3.x * v3.x + v3.y * v3.y + v3.z * v3.z + v3.w * v3.w;
      ss += __shfl_xor(ss, 1);
      ss += __shfl_xor(ss, 2);
      float inv = 1.0f / fmaxf(sqrtf(ss), 1e-12f);
      float4 o;
      o.x = v0.x * inv; o.y = v0.y * inv; o.z = v0.z * inv; o.w = v0.w * inv;
      *reinterpret_cast<float4*>(&Ks[r][c0]) = o;
      o.x = v1.x * inv; o.y = v1.y * inv; o.z = v1.z * inv; o.w = v1.w * inv;
      *reinterpret_cast<float4*>(&Ks[r][c0 + 4]) = o;
      o.x = v2.x * inv; o.y = v2.y * inv; o.z = v2.z * inv; o.w = v2.w * inv;
      *reinterpret_cast<float4*>(&Ks[r][c0 + 8]) = o;
      o.x = v3.x * inv; o.y = v3.y * inv; o.z = v3.z * inv; o.w = v3.w * inv;
      *reinterpret_cast<float4*>(&Ks[r][c0 + 12]) = o;
      const float* vsrc = ksrc + DMODEL;
      *reinterpret_cast<float4*>(&Vs[r][c0]) = *reinterpret_cast<const float4*>(vsrc);
      *reinterpret_cast<float4*>(&Vs[r][c0 + 4]) = *reinterpret_cast<const float4*>(vsrc + 4);
      *reinterpret_cast<float4*>(&Vs[r][c0 + 8]) = *reinterpret_cast<const float4*>(vsrc + 8);
      *reinterpret_cast<float4*>(&Vs[r][c0 + 12]) = *reinterpret_cast<const float4*>(vsrc + 12);
    }
    __syncthreads();

    // scores: thread (ty,tx) computes 4x4 patch
    float sc[4][4];
#pragma unroll
    for (int i = 0; i < 4; ++i)
#pragma unroll
      for (int j = 0; j < 4; ++j) sc[i][j] = 0.0f;
#pragma unroll
    for (int k4 = 0; k4 < 16; ++k4) {
      float qr[4][4], kr[4][4];
#pragma unroll
      for (int i = 0; i < 4; ++i) {
        float4 t = *reinterpret_cast<const float4*>(&Qs[ty * 4 + i][k4 * 4]);
        qr[i][0] = t.x; qr[i][1] = t.y; qr[i][2] = t.z; qr[i][3] = t.w;
      }
#pragma unroll
      for (int j = 0; j < 4; ++j) {
        float4 t = *reinterpret_cast<const float4*>(&Ks[tx * 4 + j][k4 * 4]);
        kr[j][0] = t.x; kr[j][1] = t.y; kr[j][2] = t.z; kr[j][3] = t.w;
      }
#pragma unroll
      for (int i = 0; i < 4; ++i)
#pragma unroll
        for (int j = 0; j < 4; ++j)
          sc[i][j] += qr[i][0] * kr[j][0] + qr[i][1] * kr[j][1] +
                      qr[i][2] * kr[j][2] + qr[i][3] * kr[j][3];
    }
#pragma unroll
    for (int i = 0; i < 4; ++i) {
      float rowsum = 0.0f;
#pragma unroll
      for (int j = 0; j < 4; ++j) {
        float p = __expf(scale * (sc[i][j] - 1.0f));
        Ps[ty * 4 + i][tx * 4 + j] = p;
        rowsum += p;
      }
      rowsum += __shfl_xor(rowsum, 1);
      rowsum += __shfl_xor(rowsum, 2);
      rowsum += __shfl_xor(rowsum, 4);
      rowsum += __shfl_xor(rowsum, 8);
      if (tx == 0) den[ty * 4 + i] += rowsum;
    }
    __syncthreads();

    // PV: acc[i][j] += sum_kj P[qi][kj] * V[kj][hd]
#pragma unroll
    for (int k4 = 0; k4 < 16; ++k4) {
      float pr[4][4], vr[4][4];
#pragma unroll
      for (int i = 0; i < 4; ++i) {
        float4 t = *reinterpret_cast<const float4*>(&Ps[ty * 4 + i][k4 * 4]);
        pr[i][0] = t.x; pr[i][1] = t.y; pr[i][2] = t.z; pr[i][3] = t.w;
      }
#pragma unroll
      for (int j2 = 0; j2 < 4; ++j2) {
        float4 t = *reinterpret_cast<const float4*>(&Vs[k4 * 4 + j2][tx * 4]);
        vr[j2][0] = t.x; vr[j2][1] = t.y; vr[j2][2] = t.z; vr[j2][3] = t.w;
      }
#pragma unroll
      for (int i = 0; i < 4; ++i)
#pragma unroll
        for (int j = 0; j < 4; ++j)
          acc[i][j] += pr[i][0] * vr[0][j] + pr[i][1] * vr[1][j] +
                       pr[i][2] * vr[2][j] + pr[i][3] * vr[3][j];
    }
    __syncthreads();
  }

  // finalize: divide by denominator, write ctx in [B,S,D] layout
#pragma unroll
  for (int i = 0; i < 4; ++i) {
    float invd = 1.0f / den[ty * 4 + i];
    float4 o = {acc[i][0] * invd, acc[i][1] * invd, acc[i][2] * invd, acc[i][3] * invd};
    size_t row = (size_t)(b * S_LEN + qt * 64 + ty * 4 + i);
    *reinterpret_cast<float4*>(ctx + row * DMODEL + h * HD + tx * 4) = o;
  }
}

// ------------------------------------------------------------------ launch
extern "C" void kernel_launch(void* const* d_in, const int* in_sizes, int n_in,
                              void* d_out, int out_size, void* d_ws, size_t ws_size,
                              hipStream_t stream) {
  const float* x    = (const float*)d_in[0];
  const float* wq   = (const float*)d_in[1];
  const float* bq   = (const float*)d_in[2];
  const float* wk   = (const float*)d_in[3];
  const float* bk   = (const float*)d_in[4];
  const float* wv   = (const float*)d_in[5];
  const float* bv   = (const float*)d_in[6];
  const float* wo   = (const float*)d_in[7];
  const float* bo   = (const float*)d_in[8];
  const float* w1   = (const float*)d_in[9];
  const float* b1   = (const float*)d_in[10];
  const float* w2   = (const float*)d_in[11];
  const float* b2   = (const float*)d_in[12];
  const float* ln1g = (const float*)d_in[13];
  const float* ln1b = (const float*)d_in[14];
  const float* ln2g = (const float*)d_in[15];
  const float* ln2b = (const float*)d_in[16];
  const float* lsc  = (const float*)d_in[17];
  float* y = (float*)d_out;

  char* ws = (char*)d_ws;
  float* wqkv = (float*)(ws + 0);                    // 12,582,912 B
  float* bqkv = (float*)(ws + 12582912);             //     12,288 B
  float* xn   = (float*)(ws + 12595200);             // 16,777,216 B (xn1 -> ctx -> xn2)
  float* x2   = (float*)(ws + 29372416);             // 16,777,216 B
  float* qkv  = (float*)(ws + 46149632);             // 67,108,864 B region (qkv then h1)
  float* h1   = qkv;
  float* ctx  = xn;
  // total ws need: 113,258,496 B

  concat_w<<<dim3(1024), dim3(256), 0, stream>>>(wq, wk, wv, bq, bk, bv, wqkv, bqkv);
  ln_f32<<<dim3(NROWS), dim3(256), 0, stream>>>(x, ln1g, ln1b, xn);
  gemm_f32<EPI_BIAS><<<dim3(3 * DMODEL / 128, NROWS / 128), dim3(256), 0, stream>>>(
      xn, wqkv, bqkv, nullptr, qkv, NROWS, 3 * DMODEL, DMODEL);
  flash_attn<<<dim3(S_LEN / 64, BSZ * NH), dim3(256), 0, stream>>>(qkv, lsc, ctx);
  gemm_f32<EPI_RES><<<dim3(DMODEL / 128, NROWS / 128), dim3(256), 0, stream>>>(
      ctx, wo, bo, x, x2, NROWS, DMODEL, DMODEL);
  ln_f32<<<dim3(NROWS), dim3(256), 0, stream>>>(x2, ln2g, ln2b, xn);
  gemm_f32<EPI_GELU><<<dim3(MLPD / 128, NROWS / 128), dim3(256), 0, stream>>>(
      xn, w1, b1, nullptr, h1, NROWS, MLPD, DMODEL);
  gemm_f32<EPI_RES><<<dim3(DMODEL / 128, NROWS / 128), dim3(256), 0, stream>>>(
      h1, w2, b2, x2, y, NROWS, DMODEL, MLPD);
}

// Round 3
// 488.123 us; speedup vs baseline: 5.4511x; 5.4511x over previous
//
#include <hip/hip_runtime.h>
#include <hip/hip_bf16.h>
#include <math.h>

typedef unsigned short u16;
typedef unsigned int u32;
typedef __attribute__((ext_vector_type(8))) short bf16x8;
typedef __attribute__((ext_vector_type(4))) float f32x4;

#define S_LEN 2048
#define DM 1024
#define NH 16
#define HD 64
#define MLPD 4096
#define BSZ 2
#define NROWS (BSZ * S_LEN) /* 4096 */
#define LOGMAX 4.60517018598809f /* log(1/0.01) */

__device__ __forceinline__ u16 f2bf(float f) {
  u32 u = __float_as_uint(f);
  u32 r = (u + 0x7fffu + ((u >> 16) & 1u)) >> 16;
  return (u16)r;
}
__device__ __forceinline__ float bf2f(u16 h) { return __uint_as_float(((u32)h) << 16); }
__device__ __forceinline__ u32 pk2(float a, float b) {
  return (u32)f2bf(a) | ((u32)f2bf(b) << 16);
}
__device__ __forceinline__ void gld16(const void* g, void* l) {
  __builtin_amdgcn_global_load_lds(
      (const __attribute__((address_space(1))) void*)g,
      (__attribute__((address_space(3))) void*)l, 16, 0, 0);
}

// ---------------------------------------------------- LayerNorm (fp32 -> bf16)
__global__ __launch_bounds__(256) void ln_bf16(const float* __restrict__ x,
                                               const float* __restrict__ g,
                                               const float* __restrict__ b,
                                               u16* __restrict__ out) {
  const int row = blockIdx.x;
  const int t = threadIdx.x;
  const float* xr = x + (size_t)row * DM;
  float4 v = *reinterpret_cast<const float4*>(xr + t * 4);
  float s = v.x + v.y + v.z + v.w;
  float s2 = v.x * v.x + v.y * v.y + v.z * v.z + v.w * v.w;
#pragma unroll
  for (int off = 32; off > 0; off >>= 1) {
    s += __shfl_down(s, off);
    s2 += __shfl_down(s2, off);
  }
  __shared__ float red[8];
  __shared__ float mv[2];
  const int wid = t >> 6, lane = t & 63;
  if (lane == 0) { red[wid] = s; red[wid + 4] = s2; }
  __syncthreads();
  if (t == 0) {
    float ts = red[0] + red[1] + red[2] + red[3];
    float ts2 = red[4] + red[5] + red[6] + red[7];
    float mu = ts * (1.0f / DM);
    float var = ts2 * (1.0f / DM) - mu * mu;
    mv[0] = mu;
    mv[1] = rsqrtf(var + 1e-6f);
  }
  __syncthreads();
  const float mu = mv[0], rs = mv[1];
  float4 gv = *reinterpret_cast<const float4*>(g + t * 4);
  float4 bv = *reinterpret_cast<const float4*>(b + t * 4);
  float o0 = (v.x - mu) * rs * gv.x + bv.x;
  float o1 = (v.y - mu) * rs * gv.y + bv.y;
  float o2 = (v.z - mu) * rs * gv.z + bv.z;
  float o3 = (v.w - mu) * rs * gv.w + bv.w;
  uint2 o;
  o.x = pk2(o0, o1);
  o.y = pk2(o2, o3);
  *reinterpret_cast<uint2*>(out + (size_t)row * DM + t * 4) = o;
}

// ------------------------------------- weight transpose+cast (+bias concat)
// src fp32 [K][N] -> dst bf16 [N][K]; 64x64 tiles via LDS.
__global__ __launch_bounds__(256) void prep_weights(
    const float* __restrict__ wq, const float* __restrict__ wk, const float* __restrict__ wv,
    const float* __restrict__ wo, const float* __restrict__ w1, const float* __restrict__ w2,
    const float* __restrict__ bq, const float* __restrict__ bk, const float* __restrict__ bv,
    u16* __restrict__ wqkv_t, u16* __restrict__ wo_t, u16* __restrict__ w1_t,
    u16* __restrict__ w2_t, float* __restrict__ bqkv) {
  const int tid = threadIdx.x;
  int bid = blockIdx.x;
  if (bid < 12) {
    int i = bid * 256 + tid;
    bqkv[i] = i < 1024 ? bq[i] : (i < 2048 ? bk[i - 1024] : bv[i - 2048]);
  }
  const float* src;
  u16* dst;
  int K, N;
  if (bid < 768) {
    int m = bid >> 8;
    src = (m == 0) ? wq : (m == 1 ? wk : wv);
    dst = wqkv_t + (size_t)m * 1024 * 1024;
    K = 1024; N = 1024;
    bid &= 255;
  } else if (bid < 1024) {
    src = wo; dst = wo_t; K = 1024; N = 1024; bid -= 768;
  } else if (bid < 2048) {
    src = w1; dst = w1_t; K = 1024; N = 4096; bid -= 1024;
  } else {
    src = w2; dst = w2_t; K = 4096; N = 1024; bid -= 2048;
  }
  const int ktiles = K >> 6;
  const int k0 = (bid % ktiles) << 6, n0 = (bid / ktiles) << 6;
  __shared__ float tile[64][65];
#pragma unroll
  for (int p = 0; p < 4; ++p) {
    int r = p * 16 + (tid >> 4), c = (tid & 15) * 4;
    *reinterpret_cast<float4*>(&tile[r][c]) =
        *reinterpret_cast<const float4*>(&src[(size_t)(k0 + r) * N + n0 + c]);
  }
  __syncthreads();
#pragma unroll
  for (int p = 0; p < 4; ++p) {
    int n = p * 16 + (tid >> 4), k = (tid & 15) * 4;
    uint2 o;
    o.x = pk2(tile[k][n], tile[k + 1][n]);
    o.y = pk2(tile[k + 2][n], tile[k + 3][n]);
    *reinterpret_cast<uint2*>(&dst[(size_t)(n0 + n) * K + k0 + k]) = o;
  }
}

// --------------------------------------------------------------- bf16 GEMM
// C[M,N] = A[M,K](bf16) @ Bt[N,K]^T(bf16) + bias, epilogue variants.
// 128x128 tile, BK=32, 4 waves, each wave 64x64 via 4x4 mfma_f32_16x16x32_bf16.
#define EPI_BIAS 0
#define EPI_GELU 1
#define EPI_RES 2

template <int EPI, int OUTBF>
__global__ __launch_bounds__(256) void gemm_bf16(
    const u16* __restrict__ A, const u16* __restrict__ Bt,
    const float* __restrict__ bias, const float* __restrict__ res,
    void* __restrict__ Cout, int M, int N, int K) {
  __shared__ u16 As[128 * 32];
  __shared__ u16 Bs[128 * 32];
  const int tid = threadIdx.x;
  const int wid = tid >> 6, lane = tid & 63;
  const int n0 = blockIdx.x * 128, m0 = blockIdx.y * 128;
  const int wr = wid >> 1, wc = wid & 1;

  f32x4 acc[4][4];
#pragma unroll
  for (int mi = 0; mi < 4; ++mi)
#pragma unroll
    for (int ni = 0; ni < 4; ++ni)
#pragma unroll
      for (int r = 0; r < 4; ++r) acc[mi][ni][r] = 0.0f;

  const int srow = lane >> 2;      // row within 16-row chunk
  const int skc = (lane & 3) * 8;  // k element offset

  for (int k0 = 0; k0 < K; k0 += 32) {
#pragma unroll
    for (int i = 0; i < 2; ++i) {
      int c = wid * 2 + i;
      gld16(&A[(size_t)(m0 + c * 16 + srow) * K + k0 + skc], &As[c * 512]);
      gld16(&Bt[(size_t)(n0 + c * 16 + srow) * K + k0 + skc], &Bs[c * 512]);
    }
    __syncthreads();
    const int fr = lane & 15, fg = (lane >> 4) * 8;
    bf16x8 af[4], bfr[4];
#pragma unroll
    for (int mi = 0; mi < 4; ++mi)
      af[mi] = *reinterpret_cast<const bf16x8*>(&As[(wr * 64 + mi * 16 + fr) * 32 + fg]);
#pragma unroll
    for (int ni = 0; ni < 4; ++ni)
      bfr[ni] = *reinterpret_cast<const bf16x8*>(&Bs[(wc * 64 + ni * 16 + fr) * 32 + fg]);
#pragma unroll
    for (int mi = 0; mi < 4; ++mi)
#pragma unroll
      for (int ni = 0; ni < 4; ++ni)
        acc[mi][ni] =
            __builtin_amdgcn_mfma_f32_16x16x32_bf16(af[mi], bfr[ni], acc[mi][ni], 0, 0, 0);
    __syncthreads();
  }

  const int col0 = n0 + wc * 64 + (lane & 15);
  const int r4 = (lane >> 4) * 4;
#pragma unroll
  for (int ni = 0; ni < 4; ++ni) {
    const int col = col0 + ni * 16;
    const float bb = bias[col];
#pragma unroll
    for (int mi = 0; mi < 4; ++mi) {
      const int row = m0 + wr * 64 + mi * 16 + r4;
#pragma unroll
      for (int r = 0; r < 4; ++r) {
        float v = acc[mi][ni][r] + bb;
        if (EPI == EPI_GELU) v = 0.5f * v * (1.0f + erff(v * 0.70710678118654752f));
        if (EPI == EPI_RES) v += res[(size_t)(row + r) * N + col];
        if (OUTBF)
          ((u16*)Cout)[(size_t)(row + r) * N + col] = f2bf(v);
        else
          ((float*)Cout)[(size_t)(row + r) * N + col] = v;
      }
    }
  }
}

// ------------------------------------------------------ MFMA flash attention
// qkv bf16 [B*S][3072] (q|k|v), cosine attn, fixed-shift softmax (scores<=scale).
// Block: 128 q-rows x one (b,h); 4 waves x 32 q-rows; kv tiles of 64.
__global__ __launch_bounds__(256) void flash_mfma(const u16* __restrict__ qkv,
                                                  const float* __restrict__ lsc,
                                                  u16* __restrict__ ctx) {
  __shared__ u16 Ks[64 * 72];   // [kv][d] normalized, stride 72
  __shared__ u16 Vt[64 * 72];   // [d][kv] raw, stride 72
  __shared__ u16 Ps[128 * 72];  // [q][kv] probs bf16, stride 72
  const int tid = threadIdx.x;
  const int wq = tid >> 6, lane = tid & 63;
  const int q0 = blockIdx.x * 128;
  const int bh = blockIdx.y, b = bh >> 4, h = bh & 15;
  const float scale = __expf(fminf(lsc[h], LOGMAX));
  const int fr = lane & 15, fgq = lane >> 4;

  // ---- Q fragments in registers, L2-normalized
  bf16x8 qf[2][2];
#pragma unroll
  for (int qs = 0; qs < 2; ++qs) {
    float qv[2][8];
    float ssq = 0.0f;
#pragma unroll
    for (int ds = 0; ds < 2; ++ds) {
      const u16* src = qkv + (size_t)(b * S_LEN + q0 + wq * 32 + qs * 16 + fr) * 3072 +
                       h * 64 + ds * 32 + fgq * 8;
      uint4 u = *reinterpret_cast<const uint4*>(src);
      qv[ds][0] = bf2f(u.x & 0xffff); qv[ds][1] = bf2f(u.x >> 16);
      qv[ds][2] = bf2f(u.y & 0xffff); qv[ds][3] = bf2f(u.y >> 16);
      qv[ds][4] = bf2f(u.z & 0xffff); qv[ds][5] = bf2f(u.z >> 16);
      qv[ds][6] = bf2f(u.w & 0xffff); qv[ds][7] = bf2f(u.w >> 16);
#pragma unroll
      for (int j = 0; j < 8; ++j) ssq += qv[ds][j] * qv[ds][j];
    }
    ssq += __shfl_xor(ssq, 16);
    ssq += __shfl_xor(ssq, 32);
    float inv = 1.0f / fmaxf(sqrtf(ssq), 1e-12f);
#pragma unroll
    for (int ds = 0; ds < 2; ++ds)
#pragma unroll
      for (int j = 0; j < 8; ++j) qf[qs][ds][j] = (short)f2bf(qv[ds][j] * inv);
  }

  float den[2][4];
  f32x4 octx[2][4];
#pragma unroll
  for (int qs = 0; qs < 2; ++qs)
#pragma unroll
    for (int r = 0; r < 4; ++r) {
      den[qs][r] = 0.0f;
      octx[qs][r][0] = octx[qs][r][1] = octx[qs][r][2] = octx[qs][r][3] = 0.0f;
    }

  const int sr = tid >> 2, sseg = tid & 3;  // staging: row, 8-elem segment (x2 halves)

  for (int kt = 0; kt < S_LEN / 64; ++kt) {
    // ---- stage K (normalized) and V (transposed, raw bits); both d-halves
    {
      const u16* gk = qkv + (size_t)(b * S_LEN + kt * 64 + sr) * 3072 + 1024 + h * 64 + sseg * 8;
      uint4 u0 = *reinterpret_cast<const uint4*>(gk);        // d = sseg*8 ..
      uint4 u1 = *reinterpret_cast<const uint4*>(gk + 32);   // d = 32+sseg*8 ..
      float kv[16];
      kv[0] = bf2f(u0.x & 0xffff); kv[1] = bf2f(u0.x >> 16);
      kv[2] = bf2f(u0.y & 0xffff); kv[3] = bf2f(u0.y >> 16);
      kv[4] = bf2f(u0.z & 0xffff); kv[5] = bf2f(u0.z >> 16);
      kv[6] = bf2f(u0.w & 0xffff); kv[7] = bf2f(u0.w >> 16);
      kv[8]  = bf2f(u1.x & 0xffff); kv[9]  = bf2f(u1.x >> 16);
      kv[10] = bf2f(u1.y & 0xffff); kv[11] = bf2f(u1.y >> 16);
      kv[12] = bf2f(u1.z & 0xffff); kv[13] = bf2f(u1.z >> 16);
      kv[14] = bf2f(u1.w & 0xffff); kv[15] = bf2f(u1.w >> 16);
      float ssk = 0.0f;
#pragma unroll
      for (int j = 0; j < 16; ++j) ssk += kv[j] * kv[j];
      ssk += __shfl_xor(ssk, 1);
      ssk += __shfl_xor(ssk, 2);
      float inv = 1.0f / fmaxf(sqrtf(ssk), 1e-12f);
      uint4 o;
      o.x = pk2(kv[0] * inv, kv[1] * inv);
      o.y = pk2(kv[2] * inv, kv[3] * inv);
      o.z = pk2(kv[4] * inv, kv[5] * inv);
      o.w = pk2(kv[6] * inv, kv[7] * inv);
      *reinterpret_cast<uint4*>(&Ks[sr * 72 + sseg * 8]) = o;
      o.x = pk2(kv[8] * inv, kv[9] * inv);
      o.y = pk2(kv[10] * inv, kv[11] * inv);
      o.z = pk2(kv[12] * inv, kv[13] * inv);
      o.w = pk2(kv[14] * inv, kv[15] * inv);
      *reinterpret_cast<uint4*>(&Ks[sr * 72 + 32 + sseg * 8]) = o;
      uint4 vv0 = *reinterpret_cast<const uint4*>(gk + 1024);
      uint4 vv1 = *reinterpret_cast<const uint4*>(gk + 1024 + 32);
      u16 ve[16] = {(u16)(vv0.x & 0xffff), (u16)(vv0.x >> 16), (u16)(vv0.y & 0xffff),
                    (u16)(vv0.y >> 16),    (u16)(vv0.z & 0xffff), (u16)(vv0.z >> 16),
                    (u16)(vv0.w & 0xffff), (u16)(vv0.w >> 16),
                    (u16)(vv1.x & 0xffff), (u16)(vv1.x >> 16), (u16)(vv1.y & 0xffff),
                    (u16)(vv1.y >> 16),    (u16)(vv1.z & 0xffff), (u16)(vv1.z >> 16),
                    (u16)(vv1.w & 0xffff), (u16)(vv1.w >> 16)};
#pragma unroll
      for (int j = 0; j < 8; ++j) {
        Vt[(sseg * 8 + j) * 72 + sr] = ve[j];
        Vt[(32 + sseg * 8 + j) * 72 + sr] = ve[8 + j];
      }
    }
    __syncthreads();

    // ---- QK^T: per wave 32x64 scores
    f32x4 sc[2][4];
#pragma unroll
    for (int qs = 0; qs < 2; ++qs)
#pragma unroll
      for (int ks = 0; ks < 4; ++ks)
        sc[qs][ks][0] = sc[qs][ks][1] = sc[qs][ks][2] = sc[qs][ks][3] = 0.0f;
#pragma unroll
    for (int ks = 0; ks < 4; ++ks)
#pragma unroll
      for (int ds = 0; ds < 2; ++ds) {
        bf16x8 kf = *reinterpret_cast<const bf16x8*>(&Ks[(ks * 16 + fr) * 72 + ds * 32 + fgq * 8]);
#pragma unroll
        for (int qs = 0; qs < 2; ++qs)
          sc[qs][ks] = __builtin_amdgcn_mfma_f32_16x16x32_bf16(qf[qs][ds], kf, sc[qs][ks], 0, 0, 0);
      }

    // ---- softmax partials (fixed shift by scale; p <= 1 always)
#pragma unroll
    for (int qs = 0; qs < 2; ++qs)
#pragma unroll
      for (int r = 0; r < 4; ++r) {
        const int prow = wq * 32 + qs * 16 + fgq * 4 + r;
        float ps = 0.0f;
#pragma unroll
        for (int ks = 0; ks < 4; ++ks) {
          float p = __expf(scale * (sc[qs][ks][r] - 1.0f));
          Ps[prow * 72 + ks * 16 + fr] = f2bf(p);
          ps += p;
        }
        ps += __shfl_xor(ps, 1);
        ps += __shfl_xor(ps, 2);
        ps += __shfl_xor(ps, 4);
        ps += __shfl_xor(ps, 8);
        den[qs][r] += ps;
      }

    // ---- PV
#pragma unroll
    for (int kvs = 0; kvs < 2; ++kvs) {
      bf16x8 pf0 = *reinterpret_cast<const bf16x8*>(&Ps[(wq * 32 + fr) * 72 + kvs * 32 + fgq * 8]);
      bf16x8 pf1 =
          *reinterpret_cast<const bf16x8*>(&Ps[(wq * 32 + 16 + fr) * 72 + kvs * 32 + fgq * 8]);
#pragma unroll
      for (int dsb = 0; dsb < 4; ++dsb) {
        bf16x8 vf = *reinterpret_cast<const bf16x8*>(&Vt[(dsb * 16 + fr) * 72 + kvs * 32 + fgq * 8]);
        octx[0][dsb] = __builtin_amdgcn_mfma_f32_16x16x32_bf16(pf0, vf, octx[0][dsb], 0, 0, 0);
        octx[1][dsb] = __builtin_amdgcn_mfma_f32_16x16x32_bf16(pf1, vf, octx[1][dsb], 0, 0, 0);
      }
    }
    __syncthreads();
  }

  // ---- finalize
#pragma unroll
  for (int qs = 0; qs < 2; ++qs)
#pragma unroll
    for (int r = 0; r < 4; ++r) {
      float inv = 1.0f / den[qs][r];
      const int row = q0 + wq * 32 + qs * 16 + fgq * 4 + r;
#pragma unroll
      for (int dsb = 0; dsb < 4; ++dsb)
        ctx[(size_t)(b * S_LEN + row) * DM + h * 64 + dsb * 16 + fr] =
            f2bf(octx[qs][dsb][r] * inv);
    }
}

// -------------------------------------------------------------------- launch
extern "C" void kernel_launch(void* const* d_in, const int* in_sizes, int n_in,
                              void* d_out, int out_size, void* d_ws, size_t ws_size,
                              hipStream_t stream) {
  const float* x    = (const float*)d_in[0];
  const float* wq   = (const float*)d_in[1];
  const float* bq   = (const float*)d_in[2];
  const float* wk   = (const float*)d_in[3];
  const float* bk   = (const float*)d_in[4];
  const float* wv   = (const float*)d_in[5];
  const float* bv   = (const float*)d_in[6];
  const float* wo   = (const float*)d_in[7];
  const float* bo   = (const float*)d_in[8];
  const float* w1   = (const float*)d_in[9];
  const float* b1   = (const float*)d_in[10];
  const float* w2   = (const float*)d_in[11];
  const float* b2   = (const float*)d_in[12];
  const float* ln1g = (const float*)d_in[13];
  const float* ln1b = (const float*)d_in[14];
  const float* ln2g = (const float*)d_in[15];
  const float* ln2b = (const float*)d_in[16];
  const float* lsc  = (const float*)d_in[17];

  char* ws = (char*)d_ws;
  u16* wqkv_t = (u16*)(ws + 0);          //  6,291,456
  u16* wo_t   = (u16*)(ws + 6291456);    //  2,097,152
  u16* w1_t   = (u16*)(ws + 8388608);    //  8,388,608
  u16* w2_t   = (u16*)(ws + 16777216);   //  8,388,608
  float* bqkv = (float*)(ws + 25165824); //     12,288
  u16* xn     = (u16*)(ws + 25178112);   //  8,388,608 (ln1 out, then ln2 out)
  u16* ctx    = (u16*)(ws + 33566720);   //  8,388,608
  float* x2   = (float*)(ws + 41955328); // 16,777,216
  u16* qkv    = (u16*)(ws + 58732544);   // 33,554,432 region (qkv, then h1)
  u16* h1     = qkv;

  prep_weights<<<dim3(3072), dim3(256), 0, stream>>>(wq, wk, wv, wo, w1, w2, bq, bk, bv,
                                                     wqkv_t, wo_t, w1_t, w2_t, bqkv);
  ln_bf16<<<dim3(NROWS), dim3(256), 0, stream>>>(x, ln1g, ln1b, xn);
  gemm_bf16<EPI_BIAS, 1><<<dim3(3072 / 128, NROWS / 128), dim3(256), 0, stream>>>(
      xn, wqkv_t, bqkv, nullptr, qkv, NROWS, 3072, 1024);
  flash_mfma<<<dim3(S_LEN / 128, BSZ * NH), dim3(256), 0, stream>>>(qkv, lsc, ctx);
  gemm_bf16<EPI_RES, 0><<<dim3(1024 / 128, NROWS / 128), dim3(256), 0, stream>>>(
      ctx, wo_t, bo, x, x2, NROWS, 1024, 1024);
  ln_bf16<<<dim3(NROWS), dim3(256), 0, stream>>>(x2, ln2g, ln2b, xn);
  gemm_bf16<EPI_GELU, 1><<<dim3(4096 / 128, NROWS / 128), dim3(256), 0, stream>>>(
      xn, w1_t, b1, nullptr, h1, NROWS, 4096, 1024);
  gemm_bf16<EPI_RES, 0><<<dim3(1024 / 128, NROWS / 128), dim3(256), 0, stream>>>(
      h1, w2_t, b2, x2, (float*)d_out, NROWS, 1024, 4096);
}

// Round 4
// 481.269 us; speedup vs baseline: 5.5287x; 1.0142x over previous
//
#include <hip/hip_runtime.h>
#include <hip/hip_bf16.h>
#include <math.h>

typedef unsigned short u16;
typedef unsigned int u32;
typedef __attribute__((ext_vector_type(8))) short bf16x8;
typedef __attribute__((ext_vector_type(4))) float f32x4;

#define S_LEN 2048
#define DM 1024
#define NH 16
#define HD 64
#define MLPD 4096
#define BSZ 2
#define NROWS (BSZ * S_LEN) /* 4096 */
#define LOGMAX 4.60517018598809f /* log(1/0.01) */

__device__ __forceinline__ u16 f2bf(float f) {
  u32 u = __float_as_uint(f);
  u32 r = (u + 0x7fffu + ((u >> 16) & 1u)) >> 16;
  return (u16)r;
}
__device__ __forceinline__ float bf2f(u16 h) { return __uint_as_float(((u32)h) << 16); }
__device__ __forceinline__ u32 pk2(float a, float b) {
  return (u32)f2bf(a) | ((u32)f2bf(b) << 16);
}
__device__ __forceinline__ void gld16(const void* g, void* l) {
  __builtin_amdgcn_global_load_lds(
      (const __attribute__((address_space(1))) void*)g,
      (__attribute__((address_space(3))) void*)l, 16, 0, 0);
}

// ---------------------------------------------------- LayerNorm (fp32 -> bf16)
__global__ __launch_bounds__(256) void ln_bf16(const float* __restrict__ x,
                                               const float* __restrict__ g,
                                               const float* __restrict__ b,
                                               u16* __restrict__ out) {
  const int row = blockIdx.x;
  const int t = threadIdx.x;
  const float* xr = x + (size_t)row * DM;
  float4 v = *reinterpret_cast<const float4*>(xr + t * 4);
  float s = v.x + v.y + v.z + v.w;
  float s2 = v.x * v.x + v.y * v.y + v.z * v.z + v.w * v.w;
#pragma unroll
  for (int off = 32; off > 0; off >>= 1) {
    s += __shfl_down(s, off);
    s2 += __shfl_down(s2, off);
  }
  __shared__ float red[8];
  __shared__ float mv[2];
  const int wid = t >> 6, lane = t & 63;
  if (lane == 0) { red[wid] = s; red[wid + 4] = s2; }
  __syncthreads();
  if (t == 0) {
    float ts = red[0] + red[1] + red[2] + red[3];
    float ts2 = red[4] + red[5] + red[6] + red[7];
    float mu = ts * (1.0f / DM);
    float var = ts2 * (1.0f / DM) - mu * mu;
    mv[0] = mu;
    mv[1] = rsqrtf(var + 1e-6f);
  }
  __syncthreads();
  const float mu = mv[0], rs = mv[1];
  float4 gv = *reinterpret_cast<const float4*>(g + t * 4);
  float4 bv = *reinterpret_cast<const float4*>(b + t * 4);
  float o0 = (v.x - mu) * rs * gv.x + bv.x;
  float o1 = (v.y - mu) * rs * gv.y + bv.y;
  float o2 = (v.z - mu) * rs * gv.z + bv.z;
  float o3 = (v.w - mu) * rs * gv.w + bv.w;
  uint2 o;
  o.x = pk2(o0, o1);
  o.y = pk2(o2, o3);
  *reinterpret_cast<uint2*>(out + (size_t)row * DM + t * 4) = o;
}

// ------------------------------------- weight transpose+cast (+bias concat)
// src fp32 [K][N] -> dst bf16 [N][K]; 64x64 tiles via LDS.
__global__ __launch_bounds__(256) void prep_weights(
    const float* __restrict__ wq, const float* __restrict__ wk, const float* __restrict__ wv,
    const float* __restrict__ wo, const float* __restrict__ w1, const float* __restrict__ w2,
    const float* __restrict__ bq, const float* __restrict__ bk, const float* __restrict__ bv,
    u16* __restrict__ wqkv_t, u16* __restrict__ wo_t, u16* __restrict__ w1_t,
    u16* __restrict__ w2_t, float* __restrict__ bqkv) {
  const int tid = threadIdx.x;
  int bid = blockIdx.x;
  if (bid < 12) {
    int i = bid * 256 + tid;
    bqkv[i] = i < 1024 ? bq[i] : (i < 2048 ? bk[i - 1024] : bv[i - 2048]);
  }
  const float* src;
  u16* dst;
  int K, N;
  if (bid < 768) {
    int m = bid >> 8;
    src = (m == 0) ? wq : (m == 1 ? wk : wv);
    dst = wqkv_t + (size_t)m * 1024 * 1024;
    K = 1024; N = 1024;
    bid &= 255;
  } else if (bid < 1024) {
    src = wo; dst = wo_t; K = 1024; N = 1024; bid -= 768;
  } else if (bid < 2048) {
    src = w1; dst = w1_t; K = 1024; N = 4096; bid -= 1024;
  } else {
    src = w2; dst = w2_t; K = 4096; N = 1024; bid -= 2048;
  }
  const int ktiles = K >> 6;
  const int k0 = (bid % ktiles) << 6, n0 = (bid / ktiles) << 6;
  __shared__ float tile[64][65];
#pragma unroll
  for (int p = 0; p < 4; ++p) {
    int r = p * 16 + (tid >> 4), c = (tid & 15) * 4;
    *reinterpret_cast<float4*>(&tile[r][c]) =
        *reinterpret_cast<const float4*>(&src[(size_t)(k0 + r) * N + n0 + c]);
  }
  __syncthreads();
#pragma unroll
  for (int p = 0; p < 4; ++p) {
    int n = p * 16 + (tid >> 4), k = (tid & 15) * 4;
    uint2 o;
    o.x = pk2(tile[k][n], tile[k + 1][n]);
    o.y = pk2(tile[k + 2][n], tile[k + 3][n]);
    *reinterpret_cast<uint2*>(&dst[(size_t)(n0 + n) * K + k0 + k]) = o;
  }
}

// --------------------------------------------------------------- bf16 GEMM
// C[M,N] = A[M,K](bf16) @ Bt[N,K]^T(bf16) + bias, epilogue variants.
// 128x128 tile, BK=32, 4 waves, each wave 64x64 via 4x4 mfma_f32_16x16x32_bf16.
// EPI_QKV: cols <2048 -> L2-normalized per-head rows into qkx [s][2048];
//          cols >=2048 -> raw v written transposed into vtx [bh][d][s].
#define EPI_BIAS 0
#define EPI_GELU 1
#define EPI_RES 2
#define EPI_QKV 3

template <int EPI, int OUTBF>
__global__ __launch_bounds__(256) void gemm_bf16(
    const u16* __restrict__ A, const u16* __restrict__ Bt,
    const float* __restrict__ bias, const float* __restrict__ res,
    void* __restrict__ Cout, u16* __restrict__ qkx, u16* __restrict__ vtx,
    int M, int N, int K) {
  __shared__ u16 As[128 * 32];
  __shared__ u16 Bs[128 * 32];
  const int tid = threadIdx.x;
  const int wid = tid >> 6, lane = tid & 63;
  const int n0 = blockIdx.x * 128, m0 = blockIdx.y * 128;
  const int wr = wid >> 1, wc = wid & 1;

  f32x4 acc[4][4];
#pragma unroll
  for (int mi = 0; mi < 4; ++mi)
#pragma unroll
    for (int ni = 0; ni < 4; ++ni)
#pragma unroll
      for (int r = 0; r < 4; ++r) acc[mi][ni][r] = 0.0f;

  const int srow = lane >> 2;      // row within 16-row chunk
  const int skc = (lane & 3) * 8;  // k element offset

  for (int k0 = 0; k0 < K; k0 += 32) {
#pragma unroll
    for (int i = 0; i < 2; ++i) {
      int c = wid * 2 + i;
      gld16(&A[(size_t)(m0 + c * 16 + srow) * K + k0 + skc], &As[c * 512]);
      gld16(&Bt[(size_t)(n0 + c * 16 + srow) * K + k0 + skc], &Bs[c * 512]);
    }
    __syncthreads();
    const int fr = lane & 15, fg = (lane >> 4) * 8;
    bf16x8 af[4], bfr[4];
#pragma unroll
    for (int mi = 0; mi < 4; ++mi)
      af[mi] = *reinterpret_cast<const bf16x8*>(&As[(wr * 64 + mi * 16 + fr) * 32 + fg]);
#pragma unroll
    for (int ni = 0; ni < 4; ++ni)
      bfr[ni] = *reinterpret_cast<const bf16x8*>(&Bs[(wc * 64 + ni * 16 + fr) * 32 + fg]);
#pragma unroll
    for (int mi = 0; mi < 4; ++mi)
#pragma unroll
      for (int ni = 0; ni < 4; ++ni)
        acc[mi][ni] =
            __builtin_amdgcn_mfma_f32_16x16x32_bf16(af[mi], bfr[ni], acc[mi][ni], 0, 0, 0);
    __syncthreads();
  }

  const int col0 = n0 + wc * 64 + (lane & 15);
  const int r4 = (lane >> 4) * 4;

  if constexpr (EPI == EPI_QKV) {
    float bias4[4];
#pragma unroll
    for (int ni = 0; ni < 4; ++ni) bias4[ni] = bias[col0 + ni * 16];
    const bool isV = (n0 + wc * 64) >= 2048;
#pragma unroll
    for (int mi = 0; mi < 4; ++mi) {
#pragma unroll
      for (int r = 0; r < 4; ++r) {
        const int row = m0 + wr * 64 + mi * 16 + r4 + r;
        float v[4];
#pragma unroll
        for (int ni = 0; ni < 4; ++ni) v[ni] = acc[mi][ni][r] + bias4[ni];
        if (!isV) {
          // q or k: L2-normalize over the 64-wide head (16 fr-lanes x 4 ni)
          float ss = v[0] * v[0] + v[1] * v[1] + v[2] * v[2] + v[3] * v[3];
          ss += __shfl_xor(ss, 1);
          ss += __shfl_xor(ss, 2);
          ss += __shfl_xor(ss, 4);
          ss += __shfl_xor(ss, 8);
          float inv = 1.0f / fmaxf(sqrtf(ss), 1e-12f);
#pragma unroll
          for (int ni = 0; ni < 4; ++ni)
            qkx[(size_t)row * 2048 + col0 + ni * 16] = f2bf(v[ni] * inv);
        } else {
          // v: write transposed per head: vtx[bh][d][s]
          const int b = row >> 11, sl = row & 2047;
#pragma unroll
          for (int ni = 0; ni < 4; ++ni) {
            const int col = col0 + ni * 16;
            const int h = (col - 2048) >> 6, d = col & 63;
            vtx[((size_t)(b * NH + h) * HD + d) * S_LEN + sl] = f2bf(v[ni]);
          }
        }
      }
    }
    return;
  }

  // generic epilogue
  float bias8[4];
#pragma unroll
  for (int ni = 0; ni < 4; ++ni) bias8[ni] = bias[col0 + ni * 16];
#pragma unroll
  for (int ni = 0; ni < 4; ++ni) {
    const int col = col0 + ni * 16;
    const float bb = bias8[ni];
#pragma unroll
    for (int mi = 0; mi < 4; ++mi) {
      const int row = m0 + wr * 64 + mi * 16 + r4;
#pragma unroll
      for (int r = 0; r < 4; ++r) {
        float v = acc[mi][ni][r] + bb;
        if (EPI == EPI_GELU) v = 0.5f * v * (1.0f + erff(v * 0.70710678118654752f));
        if (EPI == EPI_RES) v += res[(size_t)(row + r) * N + col];
        if (OUTBF)
          ((u16*)Cout)[(size_t)(row + r) * N + col] = f2bf(v);
        else
          ((float*)Cout)[(size_t)(row + r) * N + col] = v;
      }
    }
  }
}

// ------------------------------------------------------ MFMA flash attention
// qk bf16 [B*S][2048] pre-normalized (q|k); vt bf16 [B*H][64][S] pre-transposed.
// cosine attn, fixed-shift softmax (scores<=scale, p<=1; no online max needed).
// Block: 128 q-rows x one (b,h); 4 waves x 32 q-rows; kv tiles of 64.
__global__ __launch_bounds__(256) void flash_mfma(const u16* __restrict__ qk,
                                                  const u16* __restrict__ vt,
                                                  const float* __restrict__ lsc,
                                                  u16* __restrict__ ctx) {
  __shared__ u16 Ks[64 * 72];   // [kv][d] stride 72
  __shared__ u16 Vt[64 * 72];   // [d][kv] stride 72
  __shared__ u16 Ps[128 * 72];  // [q][kv] probs bf16, stride 72
  const int tid = threadIdx.x;
  const int wq = tid >> 6, lane = tid & 63;
  const int q0 = blockIdx.x * 128;
  const int bh = blockIdx.y, b = bh >> 4, h = bh & 15;
  const float scale = __expf(fminf(lsc[h], LOGMAX));
  const int fr = lane & 15, fgq = lane >> 4;

  // ---- Q fragments (already normalized) straight from global
  bf16x8 qf[2][2];
#pragma unroll
  for (int qs = 0; qs < 2; ++qs)
#pragma unroll
    for (int ds = 0; ds < 2; ++ds)
      qf[qs][ds] = *reinterpret_cast<const bf16x8*>(
          &qk[(size_t)(b * S_LEN + q0 + wq * 32 + qs * 16 + fr) * 2048 + h * HD + ds * 32 +
              fgq * 8]);

  float den[2][4];
  f32x4 octx[2][4];
#pragma unroll
  for (int qs = 0; qs < 2; ++qs)
#pragma unroll
    for (int r = 0; r < 4; ++r) {
      den[qs][r] = 0.0f;
      octx[qs][r][0] = octx[qs][r][1] = octx[qs][r][2] = octx[qs][r][3] = 0.0f;
    }

  const int sr = tid >> 2, sseg = tid & 3;  // staging: row, 8-elem segment (x2 halves)

  for (int kt = 0; kt < S_LEN / 64; ++kt) {
    // ---- stage K and V^T tiles: pure bit-copies, vectorized
    {
      const u16* gkp = qk + (size_t)(b * S_LEN + kt * 64 + sr) * 2048 + 1024 + h * HD + sseg * 8;
      *reinterpret_cast<uint4*>(&Ks[sr * 72 + sseg * 8]) =
          *reinterpret_cast<const uint4*>(gkp);
      *reinterpret_cast<uint4*>(&Ks[sr * 72 + 32 + sseg * 8]) =
          *reinterpret_cast<const uint4*>(gkp + 32);
      const u16* gvp = vt + (size_t)(bh * HD + sr) * S_LEN + kt * 64 + sseg * 8;
      *reinterpret_cast<uint4*>(&Vt[sr * 72 + sseg * 8]) =
          *reinterpret_cast<const uint4*>(gvp);
      *reinterpret_cast<uint4*>(&Vt[sr * 72 + 32 + sseg * 8]) =
          *reinterpret_cast<const uint4*>(gvp + 32);
    }
    __syncthreads();

    // ---- QK^T: per wave 32x64 scores
    f32x4 sc[2][4];
#pragma unroll
    for (int qs = 0; qs < 2; ++qs)
#pragma unroll
      for (int ks = 0; ks < 4; ++ks)
        sc[qs][ks][0] = sc[qs][ks][1] = sc[qs][ks][2] = sc[qs][ks][3] = 0.0f;
#pragma unroll
    for (int ks = 0; ks < 4; ++ks)
#pragma unroll
      for (int ds = 0; ds < 2; ++ds) {
        bf16x8 kf = *reinterpret_cast<const bf16x8*>(&Ks[(ks * 16 + fr) * 72 + ds * 32 + fgq * 8]);
#pragma unroll
        for (int qs = 0; qs < 2; ++qs)
          sc[qs][ks] = __builtin_amdgcn_mfma_f32_16x16x32_bf16(qf[qs][ds], kf, sc[qs][ks], 0, 0, 0);
      }

    // ---- softmax partials (fixed shift by scale; p <= 1 always)
#pragma unroll
    for (int qs = 0; qs < 2; ++qs)
#pragma unroll
      for (int r = 0; r < 4; ++r) {
        const int prow = wq * 32 + qs * 16 + fgq * 4 + r;
        float ps = 0.0f;
#pragma unroll
        for (int ks = 0; ks < 4; ++ks) {
          float p = __expf(scale * (sc[qs][ks][r] - 1.0f));
          Ps[prow * 72 + ks * 16 + fr] = f2bf(p);
          ps += p;
        }
        ps += __shfl_xor(ps, 1);
        ps += __shfl_xor(ps, 2);
        ps += __shfl_xor(ps, 4);
        ps += __shfl_xor(ps, 8);
        den[qs][r] += ps;
      }

    // ---- PV (reads only this wave's own Ps rows -> no extra barrier)
#pragma unroll
    for (int kvs = 0; kvs < 2; ++kvs) {
      bf16x8 pf0 = *reinterpret_cast<const bf16x8*>(&Ps[(wq * 32 + fr) * 72 + kvs * 32 + fgq * 8]);
      bf16x8 pf1 =
          *reinterpret_cast<const bf16x8*>(&Ps[(wq * 32 + 16 + fr) * 72 + kvs * 32 + fgq * 8]);
#pragma unroll
      for (int dsb = 0; dsb < 4; ++dsb) {
        bf16x8 vf = *reinterpret_cast<const bf16x8*>(&Vt[(dsb * 16 + fr) * 72 + kvs * 32 + fgq * 8]);
        octx[0][dsb] = __builtin_amdgcn_mfma_f32_16x16x32_bf16(pf0, vf, octx[0][dsb], 0, 0, 0);
        octx[1][dsb] = __builtin_amdgcn_mfma_f32_16x16x32_bf16(pf1, vf, octx[1][dsb], 0, 0, 0);
      }
    }
    __syncthreads();
  }

  // ---- finalize
#pragma unroll
  for (int qs = 0; qs < 2; ++qs)
#pragma unroll
    for (int r = 0; r < 4; ++r) {
      float inv = 1.0f / den[qs][r];
      const int row = q0 + wq * 32 + qs * 16 + fgq * 4 + r;
#pragma unroll
      for (int dsb = 0; dsb < 4; ++dsb)
        ctx[(size_t)(b * S_LEN + row) * DM + h * HD + dsb * 16 + fr] =
            f2bf(octx[qs][dsb][r] * inv);
    }
}

// -------------------------------------------------------------------- launch
extern "C" void kernel_launch(void* const* d_in, const int* in_sizes, int n_in,
                              void* d_out, int out_size, void* d_ws, size_t ws_size,
                              hipStream_t stream) {
  const float* x    = (const float*)d_in[0];
  const float* wq   = (const float*)d_in[1];
  const float* bq   = (const float*)d_in[2];
  const float* wk   = (const float*)d_in[3];
  const float* bk   = (const float*)d_in[4];
  const float* wv   = (const float*)d_in[5];
  const float* bv   = (const float*)d_in[6];
  const float* wo   = (const float*)d_in[7];
  const float* bo   = (const float*)d_in[8];
  const float* w1   = (const float*)d_in[9];
  const float* b1   = (const float*)d_in[10];
  const float* w2   = (const float*)d_in[11];
  const float* b2   = (const float*)d_in[12];
  const float* ln1g = (const float*)d_in[13];
  const float* ln1b = (const float*)d_in[14];
  const float* ln2g = (const float*)d_in[15];
  const float* ln2b = (const float*)d_in[16];
  const float* lsc  = (const float*)d_in[17];

  char* ws = (char*)d_ws;
  u16* wqkv_t = (u16*)(ws + 0);          //  6,291,456
  u16* wo_t   = (u16*)(ws + 6291456);    //  2,097,152
  u16* w1_t   = (u16*)(ws + 8388608);    //  8,388,608
  u16* w2_t   = (u16*)(ws + 16777216);   //  8,388,608
  float* bqkv = (float*)(ws + 25165824); //     12,288 (pad to 25178112)
  u16* xn     = (u16*)(ws + 25178112);   //  8,388,608 (ln1 out, then ln2 out)
  float* x2   = (float*)(ws + 33566720); // 16,777,216
  u16* qkbuf  = (u16*)(ws + 50343936);   // 16,777,216  [B*S][2048] normalized q|k
  u16* vtbuf  = (u16*)(ws + 67121152);   //  8,388,608  [B*H][64][S] transposed v
  u16* ctx    = (u16*)(ws + 75509760);   //  8,388,608
  u16* h1     = qkbuf;                   // 33,554,432 overlay (qk+vt+ctx dead by then)

  prep_weights<<<dim3(3072), dim3(256), 0, stream>>>(wq, wk, wv, wo, w1, w2, bq, bk, bv,
                                                     wqkv_t, wo_t, w1_t, w2_t, bqkv);
  ln_bf16<<<dim3(NROWS), dim3(256), 0, stream>>>(x, ln1g, ln1b, xn);
  gemm_bf16<EPI_QKV, 1><<<dim3(3072 / 128, NROWS / 128), dim3(256), 0, stream>>>(
      xn, wqkv_t, bqkv, nullptr, nullptr, qkbuf, vtbuf, NROWS, 3072, 1024);
  flash_mfma<<<dim3(S_LEN / 128, BSZ * NH), dim3(256), 0, stream>>>(qkbuf, vtbuf, lsc, ctx);
  gemm_bf16<EPI_RES, 0><<<dim3(1024 / 128, NROWS / 128), dim3(256), 0, stream>>>(
      ctx, wo_t, bo, x, x2, nullptr, nullptr, NROWS, 1024, 1024);
  ln_bf16<<<dim3(NROWS), dim3(256), 0, stream>>>(x2, ln2g, ln2b, xn);
  gemm_bf16<EPI_GELU, 1><<<dim3(4096 / 128, NROWS / 128), dim3(256), 0, stream>>>(
      xn, w1_t, b1, nullptr, h1, nullptr, nullptr, NROWS, 4096, 1024);
  gemm_bf16<EPI_RES, 0><<<dim3(1024 / 128, NROWS / 128), dim3(256), 0, stream>>>(
      h1, w2_t, b2, x2, (float*)d_out, nullptr, nullptr, NROWS, 1024, 4096);
}

// Round 6
// 441.922 us; speedup vs baseline: 6.0210x; 1.0890x over previous
//
#include <hip/hip_runtime.h>
#include <hip/hip_bf16.h>
#include <math.h>

typedef unsigned short u16;
typedef unsigned int u32;
typedef __attribute__((ext_vector_type(8))) short bf16x8;
typedef __attribute__((ext_vector_type(4))) float f32x4;
typedef __attribute__((ext_vector_type(16))) float f32x16;

#define S_LEN 2048
#define DM 1024
#define NH 16
#define HD 64
#define MLPD 4096
#define BSZ 2
#define NROWS (BSZ * S_LEN) /* 4096 */
#define LOGMAX 4.60517018598809f /* log(1/0.01) */

__device__ __forceinline__ u16 f2bf(float f) {
  u32 u = __float_as_uint(f);
  u32 r = (u + 0x7fffu + ((u >> 16) & 1u)) >> 16;
  return (u16)r;
}
__device__ __forceinline__ float bf2f(u16 h) { return __uint_as_float(((u32)h) << 16); }
__device__ __forceinline__ u32 pk2(float a, float b) {
  return (u32)f2bf(a) | ((u32)f2bf(b) << 16);
}
__device__ __forceinline__ u32 cvtpk(float a, float b) {
  u32 r;
  asm("v_cvt_pk_bf16_f32 %0, %1, %2" : "=v"(r) : "v"(a), "v"(b));
  return r;
}
__device__ __forceinline__ void gld16(const void* g, void* l) {
  __builtin_amdgcn_global_load_lds(
      (const __attribute__((address_space(1))) void*)g,
      (__attribute__((address_space(3))) void*)l, 16, 0, 0);
}

// ---------------------------------------------------- LayerNorm (fp32 -> bf16)
__global__ __launch_bounds__(256) void ln_bf16(const float* __restrict__ x,
                                               const float* __restrict__ g,
                                               const float* __restrict__ b,
                                               u16* __restrict__ out) {
  const int row = blockIdx.x;
  const int t = threadIdx.x;
  const float* xr = x + (size_t)row * DM;
  float4 v = *reinterpret_cast<const float4*>(xr + t * 4);
  float s = v.x + v.y + v.z + v.w;
  float s2 = v.x * v.x + v.y * v.y + v.z * v.z + v.w * v.w;
#pragma unroll
  for (int off = 32; off > 0; off >>= 1) {
    s += __shfl_down(s, off);
    s2 += __shfl_down(s2, off);
  }
  __shared__ float red[8];
  __shared__ float mv[2];
  const int wid = t >> 6, lane = t & 63;
  if (lane == 0) { red[wid] = s; red[wid + 4] = s2; }
  __syncthreads();
  if (t == 0) {
    float ts = red[0] + red[1] + red[2] + red[3];
    float ts2 = red[4] + red[5] + red[6] + red[7];
    float mu = ts * (1.0f / DM);
    float var = ts2 * (1.0f / DM) - mu * mu;
    mv[0] = mu;
    mv[1] = rsqrtf(var + 1e-6f);
  }
  __syncthreads();
  const float mu = mv[0], rs = mv[1];
  float4 gv = *reinterpret_cast<const float4*>(g + t * 4);
  float4 bv = *reinterpret_cast<const float4*>(b + t * 4);
  float o0 = (v.x - mu) * rs * gv.x + bv.x;
  float o1 = (v.y - mu) * rs * gv.y + bv.y;
  float o2 = (v.z - mu) * rs * gv.z + bv.z;
  float o3 = (v.w - mu) * rs * gv.w + bv.w;
  uint2 o;
  o.x = pk2(o0, o1);
  o.y = pk2(o2, o3);
  *reinterpret_cast<uint2*>(out + (size_t)row * DM + t * 4) = o;
}

// ------------------------------------- weight transpose+cast (+bias concat)
__global__ __launch_bounds__(256) void prep_weights(
    const float* __restrict__ wq, const float* __restrict__ wk, const float* __restrict__ wv,
    const float* __restrict__ wo, const float* __restrict__ w1, const float* __restrict__ w2,
    const float* __restrict__ bq, const float* __restrict__ bk, const float* __restrict__ bv,
    u16* __restrict__ wqkv_t, u16* __restrict__ wo_t, u16* __restrict__ w1_t,
    u16* __restrict__ w2_t, float* __restrict__ bqkv) {
  const int tid = threadIdx.x;
  int bid = blockIdx.x;
  if (bid < 12) {
    int i = bid * 256 + tid;
    bqkv[i] = i < 1024 ? bq[i] : (i < 2048 ? bk[i - 1024] : bv[i - 2048]);
  }
  const float* src;
  u16* dst;
  int K, N;
  if (bid < 768) {
    int m = bid >> 8;
    src = (m == 0) ? wq : (m == 1 ? wk : wv);
    dst = wqkv_t + (size_t)m * 1024 * 1024;
    K = 1024; N = 1024;
    bid &= 255;
  } else if (bid < 1024) {
    src = wo; dst = wo_t; K = 1024; N = 1024; bid -= 768;
  } else if (bid < 2048) {
    src = w1; dst = w1_t; K = 1024; N = 4096; bid -= 1024;
  } else {
    src = w2; dst = w2_t; K = 4096; N = 1024; bid -= 2048;
  }
  const int ktiles = K >> 6;
  const int k0 = (bid % ktiles) << 6, n0 = (bid / ktiles) << 6;
  __shared__ float tile[64][65];
#pragma unroll
  for (int p = 0; p < 4; ++p) {
    int r = p * 16 + (tid >> 4), c = (tid & 15) * 4;
    *reinterpret_cast<float4*>(&tile[r][c]) =
        *reinterpret_cast<const float4*>(&src[(size_t)(k0 + r) * N + n0 + c]);
  }
  __syncthreads();
#pragma unroll
  for (int p = 0; p < 4; ++p) {
    int n = p * 16 + (tid >> 4), k = (tid & 15) * 4;
    uint2 o;
    o.x = pk2(tile[k][n], tile[k + 1][n]);
    o.y = pk2(tile[k + 2][n], tile[k + 3][n]);
    *reinterpret_cast<uint2*>(&dst[(size_t)(n0 + n) * K + k0 + k]) = o;
  }
}

// --------------------------------------------------------------- bf16 GEMM
#define EPI_BIAS 0
#define EPI_GELU 1
#define EPI_RES 2
#define EPI_QKV 3

template <int EPI, int OUTBF>
__global__ __launch_bounds__(256) void gemm_bf16(
    const u16* __restrict__ A, const u16* __restrict__ Bt,
    const float* __restrict__ bias, const float* __restrict__ res,
    void* __restrict__ Cout, u16* __restrict__ qkx, u16* __restrict__ vtx,
    int M, int N, int K) {
  __shared__ u16 As[128 * 32];
  __shared__ u16 Bs[128 * 32];
  const int tid = threadIdx.x;
  const int wid = tid >> 6, lane = tid & 63;
  const int n0 = blockIdx.x * 128, m0 = blockIdx.y * 128;
  const int wr = wid >> 1, wc = wid & 1;

  f32x4 acc[4][4];
#pragma unroll
  for (int mi = 0; mi < 4; ++mi)
#pragma unroll
    for (int ni = 0; ni < 4; ++ni)
#pragma unroll
      for (int r = 0; r < 4; ++r) acc[mi][ni][r] = 0.0f;

  const int srow = lane >> 2;
  const int skc = (lane & 3) * 8;

  for (int k0 = 0; k0 < K; k0 += 32) {
#pragma unroll
    for (int i = 0; i < 2; ++i) {
      int c = wid * 2 + i;
      gld16(&A[(size_t)(m0 + c * 16 + srow) * K + k0 + skc], &As[c * 512]);
      gld16(&Bt[(size_t)(n0 + c * 16 + srow) * K + k0 + skc], &Bs[c * 512]);
    }
    __syncthreads();
    const int fr = lane & 15, fg = (lane >> 4) * 8;
    bf16x8 af[4], bfr[4];
#pragma unroll
    for (int mi = 0; mi < 4; ++mi)
      af[mi] = *reinterpret_cast<const bf16x8*>(&As[(wr * 64 + mi * 16 + fr) * 32 + fg]);
#pragma unroll
    for (int ni = 0; ni < 4; ++ni)
      bfr[ni] = *reinterpret_cast<const bf16x8*>(&Bs[(wc * 64 + ni * 16 + fr) * 32 + fg]);
#pragma unroll
    for (int mi = 0; mi < 4; ++mi)
#pragma unroll
      for (int ni = 0; ni < 4; ++ni)
        acc[mi][ni] =
            __builtin_amdgcn_mfma_f32_16x16x32_bf16(af[mi], bfr[ni], acc[mi][ni], 0, 0, 0);
    __syncthreads();
  }

  const int col0 = n0 + wc * 64 + (lane & 15);
  const int r4 = (lane >> 4) * 4;

  if constexpr (EPI == EPI_QKV) {
    float bias4[4];
#pragma unroll
    for (int ni = 0; ni < 4; ++ni) bias4[ni] = bias[col0 + ni * 16];
    const bool isV = (n0 + wc * 64) >= 2048;
#pragma unroll
    for (int mi = 0; mi < 4; ++mi) {
#pragma unroll
      for (int r = 0; r < 4; ++r) {
        const int row = m0 + wr * 64 + mi * 16 + r4 + r;
        float v[4];
#pragma unroll
        for (int ni = 0; ni < 4; ++ni) v[ni] = acc[mi][ni][r] + bias4[ni];
        if (!isV) {
          float ss = v[0] * v[0] + v[1] * v[1] + v[2] * v[2] + v[3] * v[3];
          ss += __shfl_xor(ss, 1);
          ss += __shfl_xor(ss, 2);
          ss += __shfl_xor(ss, 4);
          ss += __shfl_xor(ss, 8);
          float inv = 1.0f / fmaxf(sqrtf(ss), 1e-12f);
#pragma unroll
          for (int ni = 0; ni < 4; ++ni)
            qkx[(size_t)row * 2048 + col0 + ni * 16] = f2bf(v[ni] * inv);
        } else {
          const int b = row >> 11, sl = row & 2047;
#pragma unroll
          for (int ni = 0; ni < 4; ++ni) {
            const int col = col0 + ni * 16;
            const int h = (col - 2048) >> 6, d = col & 63;
            vtx[((size_t)(b * NH + h) * HD + d) * S_LEN + sl] = f2bf(v[ni]);
          }
        }
      }
    }
    return;
  }

  float bias8[4];
#pragma unroll
  for (int ni = 0; ni < 4; ++ni) bias8[ni] = bias[col0 + ni * 16];
#pragma unroll
  for (int ni = 0; ni < 4; ++ni) {
    const int col = col0 + ni * 16;
    const float bb = bias8[ni];
#pragma unroll
    for (int mi = 0; mi < 4; ++mi) {
      const int row = m0 + wr * 64 + mi * 16 + r4;
#pragma unroll
      for (int r = 0; r < 4; ++r) {
        float v = acc[mi][ni][r] + bb;
        if (EPI == EPI_GELU) v = 0.5f * v * (1.0f + erff(v * 0.70710678118654752f));
        if (EPI == EPI_RES) v += res[(size_t)(row + r) * N + col];
        if (OUTBF)
          ((u16*)Cout)[(size_t)(row + r) * N + col] = f2bf(v);
        else
          ((float*)Cout)[(size_t)(row + r) * N + col] = v;
      }
    }
  }
}

// ------------------------------------------------------ MFMA flash attention
// Swapped-operand 32x32x16 path: sc = mfma(K, Q) puts a full q-column in each
// lane (q = lane&31); P stays in registers (cvt_pk + shfl_xor(32) assembles the
// PV A-fragment). K/V double-buffered in LDS; ONE barrier per kv tile; staging
// loads issued before compute (T14). Fixed-shift softmax: p = exp(scale*(s-1)).
__global__ __launch_bounds__(256) void flash_mfma(const u16* __restrict__ qk,
                                                  const u16* __restrict__ vt,
                                                  const float* __restrict__ lsc,
                                                  u16* __restrict__ ctx) {
  __shared__ u16 Ks[2][64 * 72];  // [kv][d] stride 72
  __shared__ u16 Vt[2][64 * 72];  // [d][kv] stride 72
  __shared__ float den_s[128];
  const int tid = threadIdx.x;
  const int wq = tid >> 6, lane = tid & 63;
  const int lo5 = lane & 31, hi = lane >> 5;
  const int q0 = blockIdx.x * 128;
  const int bh = blockIdx.y, b = bh >> 4, h = bh & 15;
  const float scale = __expf(fminf(lsc[h], LOGMAX));

  // Q as B-fragments (col=q, k=d): 4 d-chunks of 16, loaded once
  bf16x8 qf[4];
#pragma unroll
  for (int dch = 0; dch < 4; ++dch)
    qf[dch] = *reinterpret_cast<const bf16x8*>(
        &qk[(size_t)(b * S_LEN + q0 + wq * 32 + lo5) * 2048 + h * HD + dch * 16 + hi * 8]);

  f32x16 octx[2];
#pragma unroll
  for (int dt = 0; dt < 2; ++dt)
#pragma unroll
    for (int e = 0; e < 16; ++e) octx[dt][e] = 0.0f;
  float den = 0.0f;

  const int sr = tid >> 2, sseg = tid & 3;
  const u16* kbase = qk + (size_t)(b * S_LEN + sr) * 2048 + 1024 + h * HD + sseg * 8;
  const u16* vbase = vt + (size_t)(bh * HD + sr) * S_LEN + sseg * 8;

  // prologue: stage tile 0 into buffer 0
  {
    uint4 k0 = *reinterpret_cast<const uint4*>(kbase);
    uint4 k1 = *reinterpret_cast<const uint4*>(kbase + 32);
    uint4 v0 = *reinterpret_cast<const uint4*>(vbase);
    uint4 v1 = *reinterpret_cast<const uint4*>(vbase + 32);
    *reinterpret_cast<uint4*>(&Ks[0][sr * 72 + sseg * 8]) = k0;
    *reinterpret_cast<uint4*>(&Ks[0][sr * 72 + 32 + sseg * 8]) = k1;
    *reinterpret_cast<uint4*>(&Vt[0][sr * 72 + sseg * 8]) = v0;
    *reinterpret_cast<uint4*>(&Vt[0][sr * 72 + 32 + sseg * 8]) = v1;
  }
  __syncthreads();

  int buf = 0;
  for (int kt = 0; kt < S_LEN / 64; ++kt) {
    const int nx = (kt + 1) & (S_LEN / 64 - 1);  // wraps; last-iter stage unused
    // T14: issue next-tile global loads before compute
    uint4 k0 = *reinterpret_cast<const uint4*>(kbase + (size_t)nx * 64 * 2048);
    uint4 k1 = *reinterpret_cast<const uint4*>(kbase + (size_t)nx * 64 * 2048 + 32);
    uint4 v0 = *reinterpret_cast<const uint4*>(vbase + nx * 64);
    uint4 v1 = *reinterpret_cast<const uint4*>(vbase + nx * 64 + 32);

    const u16* Kc = &Ks[buf][0];
    const u16* Vc = &Vt[buf][0];

    // ---- QK^T (swapped): sc[ktile] col=q (lane&31), k-rows in regs
    f32x16 sc[2];
#pragma unroll
    for (int ktile = 0; ktile < 2; ++ktile)
#pragma unroll
      for (int e = 0; e < 16; ++e) sc[ktile][e] = 0.0f;
#pragma unroll
    for (int ktile = 0; ktile < 2; ++ktile)
#pragma unroll
      for (int dch = 0; dch < 4; ++dch) {
        bf16x8 kf = *reinterpret_cast<const bf16x8*>(
            &Kc[(ktile * 32 + lo5) * 72 + dch * 16 + hi * 8]);
        sc[ktile] = __builtin_amdgcn_mfma_f32_32x32x16_bf16(kf, qf[dch], sc[ktile], 0, 0, 0);
      }

    // ---- softmax (fixed shift; p<=1) + bf16 pack, all in registers
    u32 pk[2][8];
    float ps = 0.0f;
#pragma unroll
    for (int ktile = 0; ktile < 2; ++ktile) {
      float p[16];
#pragma unroll
      for (int r = 0; r < 16; ++r) {
        p[r] = __expf(fmaf(scale, sc[ktile][r], -scale));
        ps += p[r];
      }
#pragma unroll
      for (int n = 0; n < 4; ++n) {
        pk[ktile][n * 2] = cvtpk(p[n * 4], p[n * 4 + 1]);
        pk[ktile][n * 2 + 1] = cvtpk(p[n * 4 + 2], p[n * 4 + 3]);
      }
    }
    ps += __shfl_xor(ps, 32);
    den += ps;

    // ---- PV: assemble A-fragment (8 consecutive kv per lane) via shfl_xor(32)
#pragma unroll
    for (int ktile = 0; ktile < 2; ++ktile)
#pragma unroll
      for (int cc = 0; cc < 2; ++cc) {
        u32 o0 = pk[ktile][(2 * cc) * 2], o1 = pk[ktile][(2 * cc) * 2 + 1];
        u32 e0 = pk[ktile][(2 * cc + 1) * 2], e1 = pk[ktile][(2 * cc + 1) * 2 + 1];
        u32 s0 = (u32)__shfl_xor((int)o0, 32);
        u32 s1 = (u32)__shfl_xor((int)o1, 32);
        u32 t0 = (u32)__shfl_xor((int)e0, 32);
        u32 t1 = (u32)__shfl_xor((int)e1, 32);
        union { u32 u[4]; bf16x8 v; } pf;
        pf.u[0] = hi ? t0 : o0;
        pf.u[1] = hi ? t1 : o1;
        pf.u[2] = hi ? e0 : s0;
        pf.u[3] = hi ? e1 : s1;
        const int kvo = (ktile * 2 + cc) * 16 + hi * 8;
#pragma unroll
        for (int dt = 0; dt < 2; ++dt) {
          bf16x8 vf = *reinterpret_cast<const bf16x8*>(&Vc[(dt * 32 + lo5) * 72 + kvo]);
          octx[dt] = __builtin_amdgcn_mfma_f32_32x32x16_bf16(pf.v, vf, octx[dt], 0, 0, 0);
        }
      }

    // ---- write staged regs into alternate buffer, single barrier
    *reinterpret_cast<uint4*>(&Ks[buf ^ 1][sr * 72 + sseg * 8]) = k0;
    *reinterpret_cast<uint4*>(&Ks[buf ^ 1][sr * 72 + 32 + sseg * 8]) = k1;
    *reinterpret_cast<uint4*>(&Vt[buf ^ 1][sr * 72 + sseg * 8]) = v0;
    *reinterpret_cast<uint4*>(&Vt[buf ^ 1][sr * 72 + 32 + sseg * 8]) = v1;
    __syncthreads();
    buf ^= 1;
  }

  // ---- finalize: redistribute den (lane q -> C-layout rows), write ctx
  if (hi == 0) den_s[wq * 32 + lo5] = den;
  __syncthreads();
#pragma unroll
  for (int r = 0; r < 16; ++r) {
    const int ql = (r & 3) + 8 * (r >> 2) + 4 * hi;
    const float inv = 1.0f / den_s[wq * 32 + ql];
    const size_t row = (size_t)(b * S_LEN + q0 + wq * 32 + ql);
#pragma unroll
    for (int dt = 0; dt < 2; ++dt)
      ctx[row * DM + h * HD + dt * 32 + lo5] = f2bf(octx[dt][r] * inv);
  }
}

// -------------------------------------------------------------------- launch
extern "C" void kernel_launch(void* const* d_in, const int* in_sizes, int n_in,
                              void* d_out, int out_size, void* d_ws, size_t ws_size,
                              hipStream_t stream) {
  const float* x    = (const float*)d_in[0];
  const float* wq   = (const float*)d_in[1];
  const float* bq   = (const float*)d_in[2];
  const float* wk   = (const float*)d_in[3];
  const float* bk   = (const float*)d_in[4];
  const float* wv   = (const float*)d_in[5];
  const float* bv   = (const float*)d_in[6];
  const float* wo   = (const float*)d_in[7];
  const float* bo   = (const float*)d_in[8];
  const float* w1   = (const float*)d_in[9];
  const float* b1   = (const float*)d_in[10];
  const float* w2   = (const float*)d_in[11];
  const float* b2   = (const float*)d_in[12];
  const float* ln1g = (const float*)d_in[13];
  const float* ln1b = (const float*)d_in[14];
  const float* ln2g = (const float*)d_in[15];
  const float* ln2b = (const float*)d_in[16];
  const float* lsc  = (const float*)d_in[17];

  char* ws = (char*)d_ws;
  u16* wqkv_t = (u16*)(ws + 0);          //  6,291,456
  u16* wo_t   = (u16*)(ws + 6291456);    //  2,097,152
  u16* w1_t   = (u16*)(ws + 8388608);    //  8,388,608
  u16* w2_t   = (u16*)(ws + 16777216);   //  8,388,608
  float* bqkv = (float*)(ws + 25165824); //     12,288 (pad to 25178112)
  u16* xn     = (u16*)(ws + 25178112);   //  8,388,608 (ln1 out, then ln2 out)
  float* x2   = (float*)(ws + 33566720); // 16,777,216
  u16* qkbuf  = (u16*)(ws + 50343936);   // 16,777,216  [B*S][2048] normalized q|k
  u16* vtbuf  = (u16*)(ws + 67121152);   //  8,388,608  [B*H][64][S] transposed v
  u16* ctx    = (u16*)(ws + 75509760);   //  8,388,608
  u16* h1     = qkbuf;                   // overlay (qk+vt+ctx dead by then)

  prep_weights<<<dim3(3072), dim3(256), 0, stream>>>(wq, wk, wv, wo, w1, w2, bq, bk, bv,
                                                     wqkv_t, wo_t, w1_t, w2_t, bqkv);
  ln_bf16<<<dim3(NROWS), dim3(256), 0, stream>>>(x, ln1g, ln1b, xn);
  gemm_bf16<EPI_QKV, 1><<<dim3(3072 / 128, NROWS / 128), dim3(256), 0, stream>>>(
      xn, wqkv_t, bqkv, nullptr, nullptr, qkbuf, vtbuf, NROWS, 3072, 1024);
  flash_mfma<<<dim3(S_LEN / 128, BSZ * NH), dim3(256), 0, stream>>>(qkbuf, vtbuf, lsc, ctx);
  gemm_bf16<EPI_RES, 0><<<dim3(1024 / 128, NROWS / 128), dim3(256), 0, stream>>>(
      ctx, wo_t, bo, x, x2, nullptr, nullptr, NROWS, 1024, 1024);
  ln_bf16<<<dim3(NROWS), dim3(256), 0, stream>>>(x2, ln2g, ln2b, xn);
  gemm_bf16<EPI_GELU, 1><<<dim3(4096 / 128, NROWS / 128), dim3(256), 0, stream>>>(
      xn, w1_t, b1, nullptr, h1, nullptr, nullptr, NROWS, 4096, 1024);
  gemm_bf16<EPI_RES, 0><<<dim3(1024 / 128, NROWS / 128), dim3(256), 0, stream>>>(
      h1, w2_t, b2, x2, (float*)d_out, nullptr, nullptr, NROWS, 1024, 4096);
}

// Round 7
// 422.288 us; speedup vs baseline: 6.3009x; 1.0465x over previous
//
#include <hip/hip_runtime.h>
#include <hip/hip_bf16.h>
#include <math.h>

typedef unsigned short u16;
typedef unsigned int u32;
typedef __attribute__((ext_vector_type(8))) short bf16x8;
typedef __attribute__((ext_vector_type(4))) float f32x4;
typedef __attribute__((ext_vector_type(16))) float f32x16;

#define S_LEN 2048
#define DM 1024
#define NH 16
#define HD 64
#define MLPD 4096
#define BSZ 2
#define NROWS (BSZ * S_LEN) /* 4096 */
#define LOGMAX 4.60517018598809f /* log(1/0.01) */

__device__ __forceinline__ u16 f2bf(float f) {
  u32 u = __float_as_uint(f);
  u32 r = (u + 0x7fffu + ((u >> 16) & 1u)) >> 16;
  return (u16)r;
}
__device__ __forceinline__ float bf2f(u16 h) { return __uint_as_float(((u32)h) << 16); }
__device__ __forceinline__ u32 pk2(float a, float b) {
  return (u32)f2bf(a) | ((u32)f2bf(b) << 16);
}
__device__ __forceinline__ u32 cvtpk(float a, float b) {
  u32 r;
  asm("v_cvt_pk_bf16_f32 %0, %1, %2" : "=v"(r) : "v"(a), "v"(b));
  return r;
}
__device__ __forceinline__ void gld16(const void* g, void* l) {
  __builtin_amdgcn_global_load_lds(
      (const __attribute__((address_space(1))) void*)g,
      (__attribute__((address_space(3))) void*)l, 16, 0, 0);
}

// ---------------------------------------------------- LayerNorm (fp32 -> bf16)
__global__ __launch_bounds__(256) void ln_bf16(const float* __restrict__ x,
                                               const float* __restrict__ g,
                                               const float* __restrict__ b,
                                               u16* __restrict__ out) {
  const int row = blockIdx.x;
  const int t = threadIdx.x;
  const float* xr = x + (size_t)row * DM;
  float4 v = *reinterpret_cast<const float4*>(xr + t * 4);
  float s = v.x + v.y + v.z + v.w;
  float s2 = v.x * v.x + v.y * v.y + v.z * v.z + v.w * v.w;
#pragma unroll
  for (int off = 32; off > 0; off >>= 1) {
    s += __shfl_down(s, off);
    s2 += __shfl_down(s2, off);
  }
  __shared__ float red[8];
  __shared__ float mv[2];
  const int wid = t >> 6, lane = t & 63;
  if (lane == 0) { red[wid] = s; red[wid + 4] = s2; }
  __syncthreads();
  if (t == 0) {
    float ts = red[0] + red[1] + red[2] + red[3];
    float ts2 = red[4] + red[5] + red[6] + red[7];
    float mu = ts * (1.0f / DM);
    float var = ts2 * (1.0f / DM) - mu * mu;
    mv[0] = mu;
    mv[1] = rsqrtf(var + 1e-6f);
  }
  __syncthreads();
  const float mu = mv[0], rs = mv[1];
  float4 gv = *reinterpret_cast<const float4*>(g + t * 4);
  float4 bv = *reinterpret_cast<const float4*>(b + t * 4);
  float o0 = (v.x - mu) * rs * gv.x + bv.x;
  float o1 = (v.y - mu) * rs * gv.y + bv.y;
  float o2 = (v.z - mu) * rs * gv.z + bv.z;
  float o3 = (v.w - mu) * rs * gv.w + bv.w;
  uint2 o;
  o.x = pk2(o0, o1);
  o.y = pk2(o2, o3);
  *reinterpret_cast<uint2*>(out + (size_t)row * DM + t * 4) = o;
}

// ------------------------------------- weight transpose+cast (+bias concat)
__global__ __launch_bounds__(256) void prep_weights(
    const float* __restrict__ wq, const float* __restrict__ wk, const float* __restrict__ wv,
    const float* __restrict__ wo, const float* __restrict__ w1, const float* __restrict__ w2,
    const float* __restrict__ bq, const float* __restrict__ bk, const float* __restrict__ bv,
    u16* __restrict__ wqkv_t, u16* __restrict__ wo_t, u16* __restrict__ w1_t,
    u16* __restrict__ w2_t, float* __restrict__ bqkv) {
  const int tid = threadIdx.x;
  int bid = blockIdx.x;
  if (bid < 12) {
    int i = bid * 256 + tid;
    bqkv[i] = i < 1024 ? bq[i] : (i < 2048 ? bk[i - 1024] : bv[i - 2048]);
  }
  const float* src;
  u16* dst;
  int K, N;
  if (bid < 768) {
    int m = bid >> 8;
    src = (m == 0) ? wq : (m == 1 ? wk : wv);
    dst = wqkv_t + (size_t)m * 1024 * 1024;
    K = 1024; N = 1024;
    bid &= 255;
  } else if (bid < 1024) {
    src = wo; dst = wo_t; K = 1024; N = 1024; bid -= 768;
  } else if (bid < 2048) {
    src = w1; dst = w1_t; K = 1024; N = 4096; bid -= 1024;
  } else {
    src = w2; dst = w2_t; K = 4096; N = 1024; bid -= 2048;
  }
  const int ktiles = K >> 6;
  const int k0 = (bid % ktiles) << 6, n0 = (bid / ktiles) << 6;
  __shared__ float tile[64][65];
#pragma unroll
  for (int p = 0; p < 4; ++p) {
    int r = p * 16 + (tid >> 4), c = (tid & 15) * 4;
    *reinterpret_cast<float4*>(&tile[r][c]) =
        *reinterpret_cast<const float4*>(&src[(size_t)(k0 + r) * N + n0 + c]);
  }
  __syncthreads();
#pragma unroll
  for (int p = 0; p < 4; ++p) {
    int n = p * 16 + (tid >> 4), k = (tid & 15) * 4;
    uint2 o;
    o.x = pk2(tile[k][n], tile[k + 1][n]);
    o.y = pk2(tile[k + 2][n], tile[k + 3][n]);
    *reinterpret_cast<uint2*>(&dst[(size_t)(n0 + n) * K + k0 + k]) = o;
  }
}

// --------------------------------------------------------------- bf16 GEMM
// 128x128 tile, BK=32, 4 waves. 2-phase double-buffered pipeline (T3 minimum):
// stage tile t+1 into buf^1 while computing tile t from buf; ONE
// __syncthreads() per K-step (its vmcnt(0)+lgkmcnt(0) drain is the handoff).
#define EPI_BIAS 0
#define EPI_GELU 1
#define EPI_RES 2
#define EPI_QKV 3

template <int EPI, int OUTBF>
__global__ __launch_bounds__(256) void gemm_bf16(
    const u16* __restrict__ A, const u16* __restrict__ Bt,
    const float* __restrict__ bias, const float* __restrict__ res,
    void* __restrict__ Cout, u16* __restrict__ qkx, u16* __restrict__ vtx,
    int M, int N, int K) {
  __shared__ u16 As[2][128 * 32];
  __shared__ u16 Bs[2][128 * 32];
  const int tid = threadIdx.x;
  const int wid = tid >> 6, lane = tid & 63;
  const int n0 = blockIdx.x * 128, m0 = blockIdx.y * 128;
  const int wr = wid >> 1, wc = wid & 1;

  f32x4 acc[4][4];
#pragma unroll
  for (int mi = 0; mi < 4; ++mi)
#pragma unroll
    for (int ni = 0; ni < 4; ++ni)
#pragma unroll
      for (int r = 0; r < 4; ++r) acc[mi][ni][r] = 0.0f;

  const int srow = lane >> 2;
  const int skc = (lane & 3) * 8;
  const int c0 = wid * 2, c1 = wid * 2 + 1;
  const u16* ab0 = A + (size_t)(m0 + c0 * 16 + srow) * K + skc;
  const u16* ab1 = A + (size_t)(m0 + c1 * 16 + srow) * K + skc;
  const u16* bb0 = Bt + (size_t)(n0 + c0 * 16 + srow) * K + skc;
  const u16* bb1 = Bt + (size_t)(n0 + c1 * 16 + srow) * K + skc;

  // prologue: stage tile 0 into buffer 0
  gld16(ab0, &As[0][c0 * 512]);
  gld16(ab1, &As[0][c1 * 512]);
  gld16(bb0, &Bs[0][c0 * 512]);
  gld16(bb1, &Bs[0][c1 * 512]);
  __syncthreads();

  const int fr = lane & 15, fg = (lane >> 4) * 8;
  int cur = 0;
  for (int k0 = 0; k0 < K; k0 += 32) {
    // stage next tile into the alternate buffer (overlaps with compute below)
    if (k0 + 32 < K) {
      const int nxt = cur ^ 1;
      gld16(ab0 + k0 + 32, &As[nxt][c0 * 512]);
      gld16(ab1 + k0 + 32, &As[nxt][c1 * 512]);
      gld16(bb0 + k0 + 32, &Bs[nxt][c0 * 512]);
      gld16(bb1 + k0 + 32, &Bs[nxt][c1 * 512]);
    }
    // compute current tile
    bf16x8 af[4], bfr[4];
#pragma unroll
    for (int mi = 0; mi < 4; ++mi)
      af[mi] = *reinterpret_cast<const bf16x8*>(&As[cur][(wr * 64 + mi * 16 + fr) * 32 + fg]);
#pragma unroll
    for (int ni = 0; ni < 4; ++ni)
      bfr[ni] = *reinterpret_cast<const bf16x8*>(&Bs[cur][(wc * 64 + ni * 16 + fr) * 32 + fg]);
#pragma unroll
    for (int mi = 0; mi < 4; ++mi)
#pragma unroll
      for (int ni = 0; ni < 4; ++ni)
        acc[mi][ni] =
            __builtin_amdgcn_mfma_f32_16x16x32_bf16(af[mi], bfr[ni], acc[mi][ni], 0, 0, 0);
    __syncthreads();  // drains vmcnt+lgkmcnt: staged tile ready, reads done
    cur ^= 1;
  }

  const int col0 = n0 + wc * 64 + (lane & 15);
  const int r4 = (lane >> 4) * 4;

  if constexpr (EPI == EPI_QKV) {
    float bias4[4];
#pragma unroll
    for (int ni = 0; ni < 4; ++ni) bias4[ni] = bias[col0 + ni * 16];
    const bool isV = (n0 + wc * 64) >= 2048;
#pragma unroll
    for (int mi = 0; mi < 4; ++mi) {
#pragma unroll
      for (int r = 0; r < 4; ++r) {
        const int row = m0 + wr * 64 + mi * 16 + r4 + r;
        float v[4];
#pragma unroll
        for (int ni = 0; ni < 4; ++ni) v[ni] = acc[mi][ni][r] + bias4[ni];
        if (!isV) {
          float ss = v[0] * v[0] + v[1] * v[1] + v[2] * v[2] + v[3] * v[3];
          ss += __shfl_xor(ss, 1);
          ss += __shfl_xor(ss, 2);
          ss += __shfl_xor(ss, 4);
          ss += __shfl_xor(ss, 8);
          float inv = 1.0f / fmaxf(sqrtf(ss), 1e-12f);
#pragma unroll
          for (int ni = 0; ni < 4; ++ni)
            qkx[(size_t)row * 2048 + col0 + ni * 16] = f2bf(v[ni] * inv);
        } else {
          const int b = row >> 11, sl = row & 2047;
#pragma unroll
          for (int ni = 0; ni < 4; ++ni) {
            const int col = col0 + ni * 16;
            const int h = (col - 2048) >> 6, d = col & 63;
            vtx[((size_t)(b * NH + h) * HD + d) * S_LEN + sl] = f2bf(v[ni]);
          }
        }
      }
    }
    return;
  }

  float bias8[4];
#pragma unroll
  for (int ni = 0; ni < 4; ++ni) bias8[ni] = bias[col0 + ni * 16];
#pragma unroll
  for (int ni = 0; ni < 4; ++ni) {
    const int col = col0 + ni * 16;
    const float bb = bias8[ni];
#pragma unroll
    for (int mi = 0; mi < 4; ++mi) {
      const int row = m0 + wr * 64 + mi * 16 + r4;
#pragma unroll
      for (int r = 0; r < 4; ++r) {
        float v = acc[mi][ni][r] + bb;
        if (EPI == EPI_GELU) v = 0.5f * v * (1.0f + erff(v * 0.70710678118654752f));
        if (EPI == EPI_RES) v += res[(size_t)(row + r) * N + col];
        if (OUTBF)
          ((u16*)Cout)[(size_t)(row + r) * N + col] = f2bf(v);
        else
          ((float*)Cout)[(size_t)(row + r) * N + col] = v;
      }
    }
  }
}

// ------------------------------------------------------ MFMA flash attention
// Swapped-operand 32x32x16 path: sc = mfma(K, Q) puts a full q-column in each
// lane (q = lane&31); P stays in registers (cvt_pk + shfl_xor(32) assembles the
// PV A-fragment). K/V double-buffered in LDS; ONE barrier per kv tile; staging
// loads issued before compute (T14). Fixed-shift softmax: p = exp(scale*(s-1)).
__global__ __launch_bounds__(256) void flash_mfma(const u16* __restrict__ qk,
                                                  const u16* __restrict__ vt,
                                                  const float* __restrict__ lsc,
                                                  u16* __restrict__ ctx) {
  __shared__ u16 Ks[2][64 * 72];  // [kv][d] stride 72
  __shared__ u16 Vt[2][64 * 72];  // [d][kv] stride 72
  __shared__ float den_s[128];
  const int tid = threadIdx.x;
  const int wq = tid >> 6, lane = tid & 63;
  const int lo5 = lane & 31, hi = lane >> 5;
  const int q0 = blockIdx.x * 128;
  const int bh = blockIdx.y, b = bh >> 4, h = bh & 15;
  const float scale = __expf(fminf(lsc[h], LOGMAX));

  // Q as B-fragments (col=q, k=d): 4 d-chunks of 16, loaded once
  bf16x8 qf[4];
#pragma unroll
  for (int dch = 0; dch < 4; ++dch)
    qf[dch] = *reinterpret_cast<const bf16x8*>(
        &qk[(size_t)(b * S_LEN + q0 + wq * 32 + lo5) * 2048 + h * HD + dch * 16 + hi * 8]);

  f32x16 octx[2];
#pragma unroll
  for (int dt = 0; dt < 2; ++dt)
#pragma unroll
    for (int e = 0; e < 16; ++e) octx[dt][e] = 0.0f;
  float den = 0.0f;

  const int sr = tid >> 2, sseg = tid & 3;
  const u16* kbase = qk + (size_t)(b * S_LEN + sr) * 2048 + 1024 + h * HD + sseg * 8;
  const u16* vbase = vt + (size_t)(bh * HD + sr) * S_LEN + sseg * 8;

  // prologue: stage tile 0 into buffer 0
  {
    uint4 k0 = *reinterpret_cast<const uint4*>(kbase);
    uint4 k1 = *reinterpret_cast<const uint4*>(kbase + 32);
    uint4 v0 = *reinterpret_cast<const uint4*>(vbase);
    uint4 v1 = *reinterpret_cast<const uint4*>(vbase + 32);
    *reinterpret_cast<uint4*>(&Ks[0][sr * 72 + sseg * 8]) = k0;
    *reinterpret_cast<uint4*>(&Ks[0][sr * 72 + 32 + sseg * 8]) = k1;
    *reinterpret_cast<uint4*>(&Vt[0][sr * 72 + sseg * 8]) = v0;
    *reinterpret_cast<uint4*>(&Vt[0][sr * 72 + 32 + sseg * 8]) = v1;
  }
  __syncthreads();

  int buf = 0;
  for (int kt = 0; kt < S_LEN / 64; ++kt) {
    const int nx = (kt + 1) & (S_LEN / 64 - 1);  // wraps; last-iter stage unused
    // T14: issue next-tile global loads before compute
    uint4 k0 = *reinterpret_cast<const uint4*>(kbase + (size_t)nx * 64 * 2048);
    uint4 k1 = *reinterpret_cast<const uint4*>(kbase + (size_t)nx * 64 * 2048 + 32);
    uint4 v0 = *reinterpret_cast<const uint4*>(vbase + nx * 64);
    uint4 v1 = *reinterpret_cast<const uint4*>(vbase + nx * 64 + 32);

    const u16* Kc = &Ks[buf][0];
    const u16* Vc = &Vt[buf][0];

    // ---- QK^T (swapped): sc[ktile] col=q (lane&31), k-rows in regs
    f32x16 sc[2];
#pragma unroll
    for (int ktile = 0; ktile < 2; ++ktile)
#pragma unroll
      for (int e = 0; e < 16; ++e) sc[ktile][e] = 0.0f;
#pragma unroll
    for (int ktile = 0; ktile < 2; ++ktile)
#pragma unroll
      for (int dch = 0; dch < 4; ++dch) {
        bf16x8 kf = *reinterpret_cast<const bf16x8*>(
            &Kc[(ktile * 32 + lo5) * 72 + dch * 16 + hi * 8]);
        sc[ktile] = __builtin_amdgcn_mfma_f32_32x32x16_bf16(kf, qf[dch], sc[ktile], 0, 0, 0);
      }

    // ---- softmax (fixed shift; p<=1) + bf16 pack, all in registers
    u32 pk[2][8];
    float ps = 0.0f;
#pragma unroll
    for (int ktile = 0; ktile < 2; ++ktile) {
      float p[16];
#pragma unroll
      for (int r = 0; r < 16; ++r) {
        p[r] = __expf(fmaf(scale, sc[ktile][r], -scale));
        ps += p[r];
      }
#pragma unroll
      for (int n = 0; n < 4; ++n) {
        pk[ktile][n * 2] = cvtpk(p[n * 4], p[n * 4 + 1]);
        pk[ktile][n * 2 + 1] = cvtpk(p[n * 4 + 2], p[n * 4 + 3]);
      }
    }
    ps += __shfl_xor(ps, 32);
    den += ps;

    // ---- PV: assemble A-fragment (8 consecutive kv per lane) via shfl_xor(32)
#pragma unroll
    for (int ktile = 0; ktile < 2; ++ktile)
#pragma unroll
      for (int cc = 0; cc < 2; ++cc) {
        u32 o0 = pk[ktile][(2 * cc) * 2], o1 = pk[ktile][(2 * cc) * 2 + 1];
        u32 e0 = pk[ktile][(2 * cc + 1) * 2], e1 = pk[ktile][(2 * cc + 1) * 2 + 1];
        u32 s0 = (u32)__shfl_xor((int)o0, 32);
        u32 s1 = (u32)__shfl_xor((int)o1, 32);
        u32 t0 = (u32)__shfl_xor((int)e0, 32);
        u32 t1 = (u32)__shfl_xor((int)e1, 32);
        union { u32 u[4]; bf16x8 v; } pf;
        pf.u[0] = hi ? t0 : o0;
        pf.u[1] = hi ? t1 : o1;
        pf.u[2] = hi ? e0 : s0;
        pf.u[3] = hi ? e1 : s1;
        const int kvo = (ktile * 2 + cc) * 16 + hi * 8;
#pragma unroll
        for (int dt = 0; dt < 2; ++dt) {
          bf16x8 vf = *reinterpret_cast<const bf16x8*>(&Vc[(dt * 32 + lo5) * 72 + kvo]);
          octx[dt] = __builtin_amdgcn_mfma_f32_32x32x16_bf16(pf.v, vf, octx[dt], 0, 0, 0);
        }
      }

    // ---- write staged regs into alternate buffer, single barrier
    *reinterpret_cast<uint4*>(&Ks[buf ^ 1][sr * 72 + sseg * 8]) = k0;
    *reinterpret_cast<uint4*>(&Ks[buf ^ 1][sr * 72 + 32 + sseg * 8]) = k1;
    *reinterpret_cast<uint4*>(&Vt[buf ^ 1][sr * 72 + sseg * 8]) = v0;
    *reinterpret_cast<uint4*>(&Vt[buf ^ 1][sr * 72 + 32 + sseg * 8]) = v1;
    __syncthreads();
    buf ^= 1;
  }

  // ---- finalize: redistribute den (lane q -> C-layout rows), write ctx
  if (hi == 0) den_s[wq * 32 + lo5] = den;
  __syncthreads();
#pragma unroll
  for (int r = 0; r < 16; ++r) {
    const int ql = (r & 3) + 8 * (r >> 2) + 4 * hi;
    const float inv = 1.0f / den_s[wq * 32 + ql];
    const size_t row = (size_t)(b * S_LEN + q0 + wq * 32 + ql);
#pragma unroll
    for (int dt = 0; dt < 2; ++dt)
      ctx[row * DM + h * HD + dt * 32 + lo5] = f2bf(octx[dt][r] * inv);
  }
}

// -------------------------------------------------------------------- launch
extern "C" void kernel_launch(void* const* d_in, const int* in_sizes, int n_in,
                              void* d_out, int out_size, void* d_ws, size_t ws_size,
                              hipStream_t stream) {
  const float* x    = (const float*)d_in[0];
  const float* wq   = (const float*)d_in[1];
  const float* bq   = (const float*)d_in[2];
  const float* wk   = (const float*)d_in[3];
  const float* bk   = (const float*)d_in[4];
  const float* wv   = (const float*)d_in[5];
  const float* bv   = (const float*)d_in[6];
  const float* wo   = (const float*)d_in[7];
  const float* bo   = (const float*)d_in[8];
  const float* w1   = (const float*)d_in[9];
  const float* b1   = (const float*)d_in[10];
  const float* w2   = (const float*)d_in[11];
  const float* b2   = (const float*)d_in[12];
  const float* ln1g = (const float*)d_in[13];
  const float* ln1b = (const float*)d_in[14];
  const float* ln2g = (const float*)d_in[15];
  const float* ln2b = (const float*)d_in[16];
  const float* lsc  = (const float*)d_in[17];

  char* ws = (char*)d_ws;
  u16* wqkv_t = (u16*)(ws + 0);          //  6,291,456
  u16* wo_t   = (u16*)(ws + 6291456);    //  2,097,152
  u16* w1_t   = (u16*)(ws + 8388608);    //  8,388,608
  u16* w2_t   = (u16*)(ws + 16777216);   //  8,388,608
  float* bqkv = (float*)(ws + 25165824); //     12,288 (pad to 25178112)
  u16* xn     = (u16*)(ws + 25178112);   //  8,388,608 (ln1 out, then ln2 out)
  float* x2   = (float*)(ws + 33566720); // 16,777,216
  u16* qkbuf  = (u16*)(ws + 50343936);   // 16,777,216  [B*S][2048] normalized q|k
  u16* vtbuf  = (u16*)(ws + 67121152);   //  8,388,608  [B*H][64][S] transposed v
  u16* ctx    = (u16*)(ws + 75509760);   //  8,388,608
  u16* h1     = qkbuf;                   // overlay (qk+vt+ctx dead by then)

  prep_weights<<<dim3(3072), dim3(256), 0, stream>>>(wq, wk, wv, wo, w1, w2, bq, bk, bv,
                                                     wqkv_t, wo_t, w1_t, w2_t, bqkv);
  ln_bf16<<<dim3(NROWS), dim3(256), 0, stream>>>(x, ln1g, ln1b, xn);
  gemm_bf16<EPI_QKV, 1><<<dim3(3072 / 128, NROWS / 128), dim3(256), 0, stream>>>(
      xn, wqkv_t, bqkv, nullptr, nullptr, qkbuf, vtbuf, NROWS, 3072, 1024);
  flash_mfma<<<dim3(S_LEN / 128, BSZ * NH), dim3(256), 0, stream>>>(qkbuf, vtbuf, lsc, ctx);
  gemm_bf16<EPI_RES, 0><<<dim3(1024 / 128, NROWS / 128), dim3(256), 0, stream>>>(
      ctx, wo_t, bo, x, x2, nullptr, nullptr, NROWS, 1024, 1024);
  ln_bf16<<<dim3(NROWS), dim3(256), 0, stream>>>(x2, ln2g, ln2b, xn);
  gemm_bf16<EPI_GELU, 1><<<dim3(4096 / 128, NROWS / 128), dim3(256), 0, stream>>>(
      xn, w1_t, b1, nullptr, h1, nullptr, nullptr, NROWS, 4096, 1024);
  gemm_bf16<EPI_RES, 0><<<dim3(1024 / 128, NROWS / 128), dim3(256), 0, stream>>>(
      h1, w2_t, b2, x2, (float*)d_out, nullptr, nullptr, NROWS, 1024, 4096);
}

// Round 8
// 397.245 us; speedup vs baseline: 6.6981x; 1.0630x over previous
//
#include <hip/hip_runtime.h>
#include <hip/hip_bf16.h>
#include <math.h>

typedef unsigned short u16;
typedef unsigned int u32;
typedef __attribute__((ext_vector_type(8))) short bf16x8;
typedef __attribute__((ext_vector_type(4))) float f32x4;
typedef __attribute__((ext_vector_type(16))) float f32x16;

#define S_LEN 2048
#define DM 1024
#define NH 16
#define HD 64
#define MLPD 4096
#define BSZ 2
#define NROWS (BSZ * S_LEN) /* 4096 */
#define LOGMAX 4.60517018598809f /* log(1/0.01) */

__device__ __forceinline__ u16 f2bf(float f) {
  u32 u = __float_as_uint(f);
  u32 r = (u + 0x7fffu + ((u >> 16) & 1u)) >> 16;
  return (u16)r;
}
__device__ __forceinline__ float bf2f(u16 h) { return __uint_as_float(((u32)h) << 16); }
__device__ __forceinline__ u32 pk2(float a, float b) {
  return (u32)f2bf(a) | ((u32)f2bf(b) << 16);
}
__device__ __forceinline__ u32 cvtpk(float a, float b) {
  u32 r;
  asm("v_cvt_pk_bf16_f32 %0, %1, %2" : "=v"(r) : "v"(a), "v"(b));
  return r;
}
__device__ __forceinline__ void gld16(const void* g, void* l) {
  __builtin_amdgcn_global_load_lds(
      (const __attribute__((address_space(1))) void*)g,
      (__attribute__((address_space(3))) void*)l, 16, 0, 0);
}

// ---------------------------------------------------- LayerNorm (fp32 -> bf16)
__global__ __launch_bounds__(256) void ln_bf16(const float* __restrict__ x,
                                               const float* __restrict__ g,
                                               const float* __restrict__ b,
                                               u16* __restrict__ out) {
  const int row = blockIdx.x;
  const int t = threadIdx.x;
  const float* xr = x + (size_t)row * DM;
  float4 v = *reinterpret_cast<const float4*>(xr + t * 4);
  float s = v.x + v.y + v.z + v.w;
  float s2 = v.x * v.x + v.y * v.y + v.z * v.z + v.w * v.w;
#pragma unroll
  for (int off = 32; off > 0; off >>= 1) {
    s += __shfl_down(s, off);
    s2 += __shfl_down(s2, off);
  }
  __shared__ float red[8];
  __shared__ float mv[2];
  const int wid = t >> 6, lane = t & 63;
  if (lane == 0) { red[wid] = s; red[wid + 4] = s2; }
  __syncthreads();
  if (t == 0) {
    float ts = red[0] + red[1] + red[2] + red[3];
    float ts2 = red[4] + red[5] + red[6] + red[7];
    float mu = ts * (1.0f / DM);
    float var = ts2 * (1.0f / DM) - mu * mu;
    mv[0] = mu;
    mv[1] = rsqrtf(var + 1e-6f);
  }
  __syncthreads();
  const float mu = mv[0], rs = mv[1];
  float4 gv = *reinterpret_cast<const float4*>(g + t * 4);
  float4 bv = *reinterpret_cast<const float4*>(b + t * 4);
  float o0 = (v.x - mu) * rs * gv.x + bv.x;
  float o1 = (v.y - mu) * rs * gv.y + bv.y;
  float o2 = (v.z - mu) * rs * gv.z + bv.z;
  float o3 = (v.w - mu) * rs * gv.w + bv.w;
  uint2 o;
  o.x = pk2(o0, o1);
  o.y = pk2(o2, o3);
  *reinterpret_cast<uint2*>(out + (size_t)row * DM + t * 4) = o;
}

// ------------------------------------- weight transpose+cast (+bias concat)
__global__ __launch_bounds__(256) void prep_weights(
    const float* __restrict__ wq, const float* __restrict__ wk, const float* __restrict__ wv,
    const float* __restrict__ wo, const float* __restrict__ w1, const float* __restrict__ w2,
    const float* __restrict__ bq, const float* __restrict__ bk, const float* __restrict__ bv,
    u16* __restrict__ wqkv_t, u16* __restrict__ wo_t, u16* __restrict__ w1_t,
    u16* __restrict__ w2_t, float* __restrict__ bqkv) {
  const int tid = threadIdx.x;
  int bid = blockIdx.x;
  if (bid < 12) {
    int i = bid * 256 + tid;
    bqkv[i] = i < 1024 ? bq[i] : (i < 2048 ? bk[i - 1024] : bv[i - 2048]);
  }
  const float* src;
  u16* dst;
  int K, N;
  if (bid < 768) {
    int m = bid >> 8;
    src = (m == 0) ? wq : (m == 1 ? wk : wv);
    dst = wqkv_t + (size_t)m * 1024 * 1024;
    K = 1024; N = 1024;
    bid &= 255;
  } else if (bid < 1024) {
    src = wo; dst = wo_t; K = 1024; N = 1024; bid -= 768;
  } else if (bid < 2048) {
    src = w1; dst = w1_t; K = 1024; N = 4096; bid -= 1024;
  } else {
    src = w2; dst = w2_t; K = 4096; N = 1024; bid -= 2048;
  }
  const int ktiles = K >> 6;
  const int k0 = (bid % ktiles) << 6, n0 = (bid / ktiles) << 6;
  __shared__ float tile[64][65];
#pragma unroll
  for (int p = 0; p < 4; ++p) {
    int r = p * 16 + (tid >> 4), c = (tid & 15) * 4;
    *reinterpret_cast<float4*>(&tile[r][c]) =
        *reinterpret_cast<const float4*>(&src[(size_t)(k0 + r) * N + n0 + c]);
  }
  __syncthreads();
#pragma unroll
  for (int p = 0; p < 4; ++p) {
    int n = p * 16 + (tid >> 4), k = (tid & 15) * 4;
    uint2 o;
    o.x = pk2(tile[k][n], tile[k + 1][n]);
    o.y = pk2(tile[k + 2][n], tile[k + 3][n]);
    *reinterpret_cast<uint2*>(&dst[(size_t)(n0 + n) * K + k0 + k]) = o;
  }
}

// --------------------------------------------------------------- bf16 GEMM
// 128x128 tile, BK=32, 4 waves, 2-phase double-buffered (one barrier/K-step).
// T1 XCD-chunked swizzle on (x,y). KSPLIT>1: blockIdx.z picks a K-chunk and
// writes raw fp32 partials (EPI_PART) to p0/p1; reduce_res combines.
#define EPI_BIAS 0
#define EPI_GELU 1
#define EPI_RES 2
#define EPI_QKV 3
#define EPI_PART 4

template <int EPI, int OUTBF, int KSPLIT>
__global__ __launch_bounds__(256) void gemm_bf16(
    const u16* __restrict__ A, const u16* __restrict__ Bt,
    const float* __restrict__ bias, const float* __restrict__ res,
    void* __restrict__ Cout, u16* __restrict__ qkx, u16* __restrict__ vtx,
    float* __restrict__ p0, float* __restrict__ p1,
    int M, int N, int K) {
  __shared__ u16 As[2][128 * 32];
  __shared__ u16 Bs[2][128 * 32];
  const int tid = threadIdx.x;
  const int wid = tid >> 6, lane = tid & 63;
  // XCD-chunked swizzle (requires gridDim.x*gridDim.y % 8 == 0)
  const int nwgxy = gridDim.x * gridDim.y;
  const int orig = blockIdx.y * gridDim.x + blockIdx.x;
  const int swz = (orig & 7) * (nwgxy >> 3) + (orig >> 3);
  const int bx = swz % gridDim.x, by = swz / gridDim.x;
  const int n0 = bx * 128, m0 = by * 128;
  const int wr = wid >> 1, wc = wid & 1;
  const int KC = K / KSPLIT;
  const int klo = (KSPLIT > 1) ? blockIdx.z * KC : 0;

  f32x4 acc[4][4];
#pragma unroll
  for (int mi = 0; mi < 4; ++mi)
#pragma unroll
    for (int ni = 0; ni < 4; ++ni)
#pragma unroll
      for (int r = 0; r < 4; ++r) acc[mi][ni][r] = 0.0f;

  const int srow = lane >> 2;
  const int skc = (lane & 3) * 8;
  const int c0 = wid * 2, c1 = wid * 2 + 1;
  const u16* ab0 = A + (size_t)(m0 + c0 * 16 + srow) * K + klo + skc;
  const u16* ab1 = A + (size_t)(m0 + c1 * 16 + srow) * K + klo + skc;
  const u16* bb0 = Bt + (size_t)(n0 + c0 * 16 + srow) * K + klo + skc;
  const u16* bb1 = Bt + (size_t)(n0 + c1 * 16 + srow) * K + klo + skc;

  // prologue: stage tile 0 into buffer 0
  gld16(ab0, &As[0][c0 * 512]);
  gld16(ab1, &As[0][c1 * 512]);
  gld16(bb0, &Bs[0][c0 * 512]);
  gld16(bb1, &Bs[0][c1 * 512]);
  __syncthreads();

  const int fr = lane & 15, fg = (lane >> 4) * 8;
  int cur = 0;
  for (int k0 = 0; k0 < KC; k0 += 32) {
    if (k0 + 32 < KC) {
      const int nxt = cur ^ 1;
      gld16(ab0 + k0 + 32, &As[nxt][c0 * 512]);
      gld16(ab1 + k0 + 32, &As[nxt][c1 * 512]);
      gld16(bb0 + k0 + 32, &Bs[nxt][c0 * 512]);
      gld16(bb1 + k0 + 32, &Bs[nxt][c1 * 512]);
    }
    bf16x8 af[4], bfr[4];
#pragma unroll
    for (int mi = 0; mi < 4; ++mi)
      af[mi] = *reinterpret_cast<const bf16x8*>(&As[cur][(wr * 64 + mi * 16 + fr) * 32 + fg]);
#pragma unroll
    for (int ni = 0; ni < 4; ++ni)
      bfr[ni] = *reinterpret_cast<const bf16x8*>(&Bs[cur][(wc * 64 + ni * 16 + fr) * 32 + fg]);
#pragma unroll
    for (int mi = 0; mi < 4; ++mi)
#pragma unroll
      for (int ni = 0; ni < 4; ++ni)
        acc[mi][ni] =
            __builtin_amdgcn_mfma_f32_16x16x32_bf16(af[mi], bfr[ni], acc[mi][ni], 0, 0, 0);
    __syncthreads();  // drains vmcnt+lgkmcnt: staged tile ready, reads done
    cur ^= 1;
  }

  const int col0 = n0 + wc * 64 + (lane & 15);
  const int r4 = (lane >> 4) * 4;

  if constexpr (EPI == EPI_PART) {
    float* dst = (KSPLIT > 1 && blockIdx.z) ? p1 : p0;
#pragma unroll
    for (int ni = 0; ni < 4; ++ni) {
      const int col = col0 + ni * 16;
#pragma unroll
      for (int mi = 0; mi < 4; ++mi) {
        const int row = m0 + wr * 64 + mi * 16 + r4;
#pragma unroll
        for (int r = 0; r < 4; ++r) dst[(size_t)(row + r) * N + col] = acc[mi][ni][r];
      }
    }
    return;
  }

  if constexpr (EPI == EPI_QKV) {
    float bias4[4];
#pragma unroll
    for (int ni = 0; ni < 4; ++ni) bias4[ni] = bias[col0 + ni * 16];
    const bool isV = (n0 + wc * 64) >= 2048;
#pragma unroll
    for (int mi = 0; mi < 4; ++mi) {
#pragma unroll
      for (int r = 0; r < 4; ++r) {
        const int row = m0 + wr * 64 + mi * 16 + r4 + r;
        float v[4];
#pragma unroll
        for (int ni = 0; ni < 4; ++ni) v[ni] = acc[mi][ni][r] + bias4[ni];
        if (!isV) {
          float ss = v[0] * v[0] + v[1] * v[1] + v[2] * v[2] + v[3] * v[3];
          ss += __shfl_xor(ss, 1);
          ss += __shfl_xor(ss, 2);
          ss += __shfl_xor(ss, 4);
          ss += __shfl_xor(ss, 8);
          float inv = 1.0f / fmaxf(sqrtf(ss), 1e-12f);
#pragma unroll
          for (int ni = 0; ni < 4; ++ni)
            qkx[(size_t)row * 2048 + col0 + ni * 16] = f2bf(v[ni] * inv);
        } else {
          const int b = row >> 11, sl = row & 2047;
#pragma unroll
          for (int ni = 0; ni < 4; ++ni) {
            const int col = col0 + ni * 16;
            const int h = (col - 2048) >> 6, d = col & 63;
            vtx[((size_t)(b * NH + h) * HD + d) * S_LEN + sl] = f2bf(v[ni]);
          }
        }
      }
    }
    return;
  }

  float bias8[4];
#pragma unroll
  for (int ni = 0; ni < 4; ++ni) bias8[ni] = bias[col0 + ni * 16];
#pragma unroll
  for (int ni = 0; ni < 4; ++ni) {
    const int col = col0 + ni * 16;
    const float bb = bias8[ni];
#pragma unroll
    for (int mi = 0; mi < 4; ++mi) {
      const int row = m0 + wr * 64 + mi * 16 + r4;
#pragma unroll
      for (int r = 0; r < 4; ++r) {
        float v = acc[mi][ni][r] + bb;
        if (EPI == EPI_GELU) v = 0.5f * v * (1.0f + erff(v * 0.70710678118654752f));
        if (EPI == EPI_RES) v += res[(size_t)(row + r) * N + col];
        if (OUTBF)
          ((u16*)Cout)[(size_t)(row + r) * N + col] = f2bf(v);
        else
          ((float*)Cout)[(size_t)(row + r) * N + col] = v;
      }
    }
  }
}

// ----------------------------------------- split-K reduce (+bias +residual)
__global__ __launch_bounds__(256) void reduce_res(
    const float* __restrict__ p0, const float* __restrict__ p1,
    const float* __restrict__ bias, const float* __restrict__ res,
    float* __restrict__ out, int N) {
  const int i = (blockIdx.x * 256 + threadIdx.x) * 4;
  float4 a = *reinterpret_cast<const float4*>(p0 + i);
  float4 b = *reinterpret_cast<const float4*>(p1 + i);
  float4 r = *reinterpret_cast<const float4*>(res + i);
  float4 bb = *reinterpret_cast<const float4*>(bias + (i & (N - 1)));
  float4 o = {a.x + b.x + r.x + bb.x, a.y + b.y + r.y + bb.y,
              a.z + b.z + r.z + bb.z, a.w + b.w + r.w + bb.w};
  *reinterpret_cast<float4*>(out + i) = o;
}

// ------------------------------------------------------ MFMA flash attention
// Swapped-operand 32x32x16 path; P in registers; K/V double-buffered; one
// barrier per kv tile. Fixed-shift softmax: p = exp(scale*(s-1)).
__global__ __launch_bounds__(256) void flash_mfma(const u16* __restrict__ qk,
                                                  const u16* __restrict__ vt,
                                                  const float* __restrict__ lsc,
                                                  u16* __restrict__ ctx) {
  __shared__ u16 Ks[2][64 * 72];  // [kv][d] stride 72
  __shared__ u16 Vt[2][64 * 72];  // [d][kv] stride 72
  __shared__ float den_s[128];
  const int tid = threadIdx.x;
  const int wq = tid >> 6, lane = tid & 63;
  const int lo5 = lane & 31, hi = lane >> 5;
  // XCD-chunked swizzle over (qt, bh)
  const int nwg = gridDim.x * gridDim.y;
  const int orig = blockIdx.y * gridDim.x + blockIdx.x;
  const int swz = (orig & 7) * (nwg >> 3) + (orig >> 3);
  const int qt = swz % gridDim.x, bh = swz / gridDim.x;
  const int q0 = qt * 128;
  const int b = bh >> 4, h = bh & 15;
  const float scale = __expf(fminf(lsc[h], LOGMAX));

  // Q as B-fragments (col=q, k=d): 4 d-chunks of 16, loaded once
  bf16x8 qf[4];
#pragma unroll
  for (int dch = 0; dch < 4; ++dch)
    qf[dch] = *reinterpret_cast<const bf16x8*>(
        &qk[(size_t)(b * S_LEN + q0 + wq * 32 + lo5) * 2048 + h * HD + dch * 16 + hi * 8]);

  f32x16 octx[2];
#pragma unroll
  for (int dt = 0; dt < 2; ++dt)
#pragma unroll
    for (int e = 0; e < 16; ++e) octx[dt][e] = 0.0f;
  float den = 0.0f;

  const int sr = tid >> 2, sseg = tid & 3;
  const u16* kbase = qk + (size_t)(b * S_LEN + sr) * 2048 + 1024 + h * HD + sseg * 8;
  const u16* vbase = vt + (size_t)(bh * HD + sr) * S_LEN + sseg * 8;

  {
    uint4 k0 = *reinterpret_cast<const uint4*>(kbase);
    uint4 k1 = *reinterpret_cast<const uint4*>(kbase + 32);
    uint4 v0 = *reinterpret_cast<const uint4*>(vbase);
    uint4 v1 = *reinterpret_cast<const uint4*>(vbase + 32);
    *reinterpret_cast<uint4*>(&Ks[0][sr * 72 + sseg * 8]) = k0;
    *reinterpret_cast<uint4*>(&Ks[0][sr * 72 + 32 + sseg * 8]) = k1;
    *reinterpret_cast<uint4*>(&Vt[0][sr * 72 + sseg * 8]) = v0;
    *reinterpret_cast<uint4*>(&Vt[0][sr * 72 + 32 + sseg * 8]) = v1;
  }
  __syncthreads();

  int buf = 0;
  for (int kt = 0; kt < S_LEN / 64; ++kt) {
    const int nx = (kt + 1) & (S_LEN / 64 - 1);
    uint4 k0 = *reinterpret_cast<const uint4*>(kbase + (size_t)nx * 64 * 2048);
    uint4 k1 = *reinterpret_cast<const uint4*>(kbase + (size_t)nx * 64 * 2048 + 32);
    uint4 v0 = *reinterpret_cast<const uint4*>(vbase + nx * 64);
    uint4 v1 = *reinterpret_cast<const uint4*>(vbase + nx * 64 + 32);

    const u16* Kc = &Ks[buf][0];
    const u16* Vc = &Vt[buf][0];

    f32x16 sc[2];
#pragma unroll
    for (int ktile = 0; ktile < 2; ++ktile)
#pragma unroll
      for (int e = 0; e < 16; ++e) sc[ktile][e] = 0.0f;
#pragma unroll
    for (int ktile = 0; ktile < 2; ++ktile)
#pragma unroll
      for (int dch = 0; dch < 4; ++dch) {
        bf16x8 kf = *reinterpret_cast<const bf16x8*>(
            &Kc[(ktile * 32 + lo5) * 72 + dch * 16 + hi * 8]);
        sc[ktile] = __builtin_amdgcn_mfma_f32_32x32x16_bf16(kf, qf[dch], sc[ktile], 0, 0, 0);
      }

    u32 pk[2][8];
    float ps = 0.0f;
#pragma unroll
    for (int ktile = 0; ktile < 2; ++ktile) {
      float p[16];
#pragma unroll
      for (int r = 0; r < 16; ++r) {
        p[r] = __expf(fmaf(scale, sc[ktile][r], -scale));
        ps += p[r];
      }
#pragma unroll
      for (int n = 0; n < 4; ++n) {
        pk[ktile][n * 2] = cvtpk(p[n * 4], p[n * 4 + 1]);
        pk[ktile][n * 2 + 1] = cvtpk(p[n * 4 + 2], p[n * 4 + 3]);
      }
    }
    ps += __shfl_xor(ps, 32);
    den += ps;

#pragma unroll
    for (int ktile = 0; ktile < 2; ++ktile)
#pragma unroll
      for (int cc = 0; cc < 2; ++cc) {
        u32 o0 = pk[ktile][(2 * cc) * 2], o1 = pk[ktile][(2 * cc) * 2 + 1];
        u32 e0 = pk[ktile][(2 * cc + 1) * 2], e1 = pk[ktile][(2 * cc + 1) * 2 + 1];
        u32 s0 = (u32)__shfl_xor((int)o0, 32);
        u32 s1 = (u32)__shfl_xor((int)o1, 32);
        u32 t0 = (u32)__shfl_xor((int)e0, 32);
        u32 t1 = (u32)__shfl_xor((int)e1, 32);
        union { u32 u[4]; bf16x8 v; } pf;
        pf.u[0] = hi ? t0 : o0;
        pf.u[1] = hi ? t1 : o1;
        pf.u[2] = hi ? e0 : s0;
        pf.u[3] = hi ? e1 : s1;
        const int kvo = (ktile * 2 + cc) * 16 + hi * 8;
#pragma unroll
        for (int dt = 0; dt < 2; ++dt) {
          bf16x8 vf = *reinterpret_cast<const bf16x8*>(&Vc[(dt * 32 + lo5) * 72 + kvo]);
          octx[dt] = __builtin_amdgcn_mfma_f32_32x32x16_bf16(pf.v, vf, octx[dt], 0, 0, 0);
        }
      }

    *reinterpret_cast<uint4*>(&Ks[buf ^ 1][sr * 72 + sseg * 8]) = k0;
    *reinterpret_cast<uint4*>(&Ks[buf ^ 1][sr * 72 + 32 + sseg * 8]) = k1;
    *reinterpret_cast<uint4*>(&Vt[buf ^ 1][sr * 72 + sseg * 8]) = v0;
    *reinterpret_cast<uint4*>(&Vt[buf ^ 1][sr * 72 + 32 + sseg * 8]) = v1;
    __syncthreads();
    buf ^= 1;
  }

  if (hi == 0) den_s[wq * 32 + lo5] = den;
  __syncthreads();
#pragma unroll
  for (int r = 0; r < 16; ++r) {
    const int ql = (r & 3) + 8 * (r >> 2) + 4 * hi;
    const float inv = 1.0f / den_s[wq * 32 + ql];
    const size_t row = (size_t)(b * S_LEN + q0 + wq * 32 + ql);
#pragma unroll
    for (int dt = 0; dt < 2; ++dt)
      ctx[row * DM + h * HD + dt * 32 + lo5] = f2bf(octx[dt][r] * inv);
  }
}

// -------------------------------------------------------------------- launch
extern "C" void kernel_launch(void* const* d_in, const int* in_sizes, int n_in,
                              void* d_out, int out_size, void* d_ws, size_t ws_size,
                              hipStream_t stream) {
  const float* x    = (const float*)d_in[0];
  const float* wq   = (const float*)d_in[1];
  const float* bq   = (const float*)d_in[2];
  const float* wk   = (const float*)d_in[3];
  const float* bk   = (const float*)d_in[4];
  const float* wv   = (const float*)d_in[5];
  const float* bv   = (const float*)d_in[6];
  const float* wo   = (const float*)d_in[7];
  const float* bo   = (const float*)d_in[8];
  const float* w1   = (const float*)d_in[9];
  const float* b1   = (const float*)d_in[10];
  const float* w2   = (const float*)d_in[11];
  const float* b2   = (const float*)d_in[12];
  const float* ln1g = (const float*)d_in[13];
  const float* ln1b = (const float*)d_in[14];
  const float* ln2g = (const float*)d_in[15];
  const float* ln2b = (const float*)d_in[16];
  const float* lsc  = (const float*)d_in[17];

  char* ws = (char*)d_ws;
  u16* wqkv_t = (u16*)(ws + 0);          //  6,291,456
  u16* wo_t   = (u16*)(ws + 6291456);    //  2,097,152
  u16* w1_t   = (u16*)(ws + 8388608);    //  8,388,608
  u16* w2_t   = (u16*)(ws + 16777216);   //  8,388,608
  float* bqkv = (float*)(ws + 25165824); //     12,288 (pad to 25178112)
  u16* xn     = (u16*)(ws + 25178112);   //  8,388,608 (ln1 out, then ln2 out)
  float* x2   = (float*)(ws + 33566720); // 16,777,216
  u16* qkbuf  = (u16*)(ws + 50343936);   // 16,777,216  [B*S][2048] normalized q|k
  u16* vtbuf  = (u16*)(ws + 67121152);   //  8,388,608  [B*H][64][S] transposed v
  u16* ctx    = (u16*)(ws + 75509760);   //  8,388,608
  u16* h1     = qkbuf;                   // overlay (qk+vt+ctx dead by then)
  // split-K partials (16 MB each), overlaid on dead regions:
  float* partA = (float*)(ws + 50343936);  // WO p0: qkbuf region (dead post-flash)
  float* partB = (float*)(ws + 83898368);  // shared p1 tail (new 16 MB)
  float* partC = (float*)(ws + 0);         // MLP2 p0: weight region (dead by then)
  // high-water: 100,675,584 B

  prep_weights<<<dim3(3072), dim3(256), 0, stream>>>(wq, wk, wv, wo, w1, w2, bq, bk, bv,
                                                     wqkv_t, wo_t, w1_t, w2_t, bqkv);
  ln_bf16<<<dim3(NROWS), dim3(256), 0, stream>>>(x, ln1g, ln1b, xn);
  gemm_bf16<EPI_QKV, 1, 1><<<dim3(3072 / 128, NROWS / 128), dim3(256), 0, stream>>>(
      xn, wqkv_t, bqkv, nullptr, nullptr, qkbuf, vtbuf, nullptr, nullptr, NROWS, 3072, 1024);
  flash_mfma<<<dim3(S_LEN / 128, BSZ * NH), dim3(256), 0, stream>>>(qkbuf, vtbuf, lsc, ctx);
  gemm_bf16<EPI_PART, 0, 2><<<dim3(1024 / 128, NROWS / 128, 2), dim3(256), 0, stream>>>(
      ctx, wo_t, nullptr, nullptr, nullptr, nullptr, nullptr, partA, partB, NROWS, 1024, 1024);
  reduce_res<<<dim3(NROWS * 1024 / 1024), dim3(256), 0, stream>>>(partA, partB, bo, x, x2, 1024);
  ln_bf16<<<dim3(NROWS), dim3(256), 0, stream>>>(x2, ln2g, ln2b, xn);
  gemm_bf16<EPI_GELU, 1, 1><<<dim3(4096 / 128, NROWS / 128), dim3(256), 0, stream>>>(
      xn, w1_t, b1, nullptr, h1, nullptr, nullptr, nullptr, nullptr, NROWS, 4096, 1024);
  gemm_bf16<EPI_PART, 0, 2><<<dim3(1024 / 128, NROWS / 128, 2), dim3(256), 0, stream>>>(
      h1, w2_t, nullptr, nullptr, nullptr, nullptr, nullptr, partC, partB, NROWS, 1024, 4096);
  reduce_res<<<dim3(NROWS * 1024 / 1024), dim3(256), 0, stream>>>(partC, partB, b2, x2,
                                                                  (float*)d_out, 1024);
}